// Round 3
// baseline (2215.151 us; speedup 1.0000x reference)
//
#include <hip/hip_runtime.h>
#include <hip/hip_bf16.h>

#define N_ATOMS 131072
#define N_EDGES 524288
#define N_MOLS  2048
#define DD      128   // n_atom_basis
#define FF      128   // n_filters
#define GG      50    // n_gaussians
#define TT      3

typedef __hip_bfloat16 bf16;
typedef __attribute__((ext_vector_type(8))) short short8;
typedef __attribute__((ext_vector_type(4))) float floatx4;

__device__ __forceinline__ float b2f(bf16 v) { return __bfloat162float(v); }
__device__ __forceinline__ bf16  f2b(float v) { return __float2bfloat16(v); }

// unpack two bf16 (packed in a uint, low half = lower address) to float2
__device__ __forceinline__ float2 up2(unsigned int u) {
    float2 f;
    f.x = __uint_as_float(u << 16);
    f.y = __uint_as_float(u & 0xffff0000u);
    return f;
}

// shifted softplus: softplus(x) - ln2, numerically stable
__device__ __forceinline__ float sspf(float x) {
    return fmaxf(x, 0.f) + log1pf(__expf(-fabsf(x))) - 0.69314718056f;
}

// ---------------------------------------------------------------------------
// MFMA helpers.  A tile: [128 rows][136] bf16 LDS (stride 136).
// B tile: [n][72] bf16 LDS holding B^T chunk: B[n][kk], kk<64.
// Block = 256 threads = 4 waves; wave w owns output rows [32w, 32w+32).
// 16x16x32 bf16 layouts: A[m=lane&15][k=q*8+j], B[k=q*8+j][n=lane&15],
// D[row=q*4+reg][col=lane&15].  (verified, learn_hip m89)
// ---------------------------------------------------------------------------
template <int NCT>
__device__ __forceinline__ void mfma_half(const bf16* A, const bf16* B,
                                          floatx4 (&acc)[2][NCT],
                                          int kA, int wave, int q, int ln) {
#pragma unroll
    for (int k0 = 0; k0 < 64; k0 += 32) {
        short8 a0 = *(const short8*)(A + (wave * 32 + ln) * 136 + kA + k0 + q * 8);
        short8 a1 = *(const short8*)(A + (wave * 32 + 16 + ln) * 136 + kA + k0 + q * 8);
#pragma unroll
        for (int ct = 0; ct < NCT; ct++) {
            short8 b = *(const short8*)(B + (ct * 16 + ln) * 72 + k0 + q * 8);
            acc[0][ct] = __builtin_amdgcn_mfma_f32_16x16x32_bf16(a0, b, acc[0][ct], 0, 0, 0);
            acc[1][ct] = __builtin_amdgcn_mfma_f32_16x16x32_bf16(a1, b, acc[1][ct], 0, 0, 0);
        }
    }
}

__device__ __forceinline__ void stage_b(bf16* B, const bf16* WT, int k0,
                                        int nrows, int ldk, int tid) {
    for (int i = tid; i < nrows * 8; i += 256) {
        int n = i >> 3, kc = i & 7;
        *(short8*)(B + n * 72 + kc * 8) =
            *(const short8*)(WT + n * ldk + k0 + kc * 8);
    }
}

// ---------------------------------------------------------------------------
__global__ __launch_bounds__(256) void k_init(const float* __restrict__ emb,
                                              const int* __restrict__ z,
                                              float* __restrict__ r) {
    int idx = blockIdx.x * 256 + threadIdx.x;
    int atom = idx >> 7, col = idx & 127;
    r[idx] = emb[z[atom] * DD + col];
}

__global__ __launch_bounds__(256) void k_dist(const float* __restrict__ xyz,
                                              const int* __restrict__ a,
                                              float* __restrict__ dArr,
                                              float* __restrict__ cArr,
                                              float* __restrict__ molE) {
    int e = blockIdx.x * 256 + threadIdx.x;
    if (e < N_MOLS) molE[e] = 0.f;
    int A0 = a[2 * e], A1 = a[2 * e + 1];
    float dx = xyz[3 * A0]     - xyz[3 * A1];
    float dy = xyz[3 * A0 + 1] - xyz[3 * A1 + 1];
    float dz = xyz[3 * A0 + 2] - xyz[3 * A1 + 2];
    float d = sqrtf(dx * dx + dy * dy + dz * dz);
    dArr[e] = d;
    cArr[e] = 0.5f * (__cosf(d * 0.6283185307179586f) + 1.f);
}

__global__ __launch_bounds__(256) void k_wt(const float* __restrict__ fw1,
                                            const float* __restrict__ fw2,
                                            const float* __restrict__ win,
                                            const float* __restrict__ wout1,
                                            const float* __restrict__ wout2,
                                            const float* __restrict__ wa1,
                                            bf16* __restrict__ fw1T, bf16* __restrict__ fw2T,
                                            bf16* __restrict__ winT, bf16* __restrict__ wout1T,
                                            bf16* __restrict__ wout2T, bf16* __restrict__ wa1T) {
    int idx = blockIdx.x * 256 + threadIdx.x;
    if (idx < 3 * 128 * 64) {
        int t = idx / 8192, j = idx % 8192;
        int n = j >> 6, k = j & 63;
        fw1T[idx] = (k < GG) ? f2b(fw1[t * GG * FF + k * FF + n]) : f2b(0.f);
        return;
    }
    idx -= 3 * 128 * 64;
    if (idx < 3 * 16384) { int t = idx / 16384, j = idx % 16384; int n = j >> 7, k = j & 127;
        fw2T[idx] = f2b(fw2[t * 16384 + k * 128 + n]); return; }
    idx -= 3 * 16384;
    if (idx < 3 * 16384) { int t = idx / 16384, j = idx % 16384; int n = j >> 7, k = j & 127;
        winT[idx] = f2b(win[t * 16384 + k * 128 + n]); return; }
    idx -= 3 * 16384;
    if (idx < 3 * 16384) { int t = idx / 16384, j = idx % 16384; int n = j >> 7, k = j & 127;
        wout1T[idx] = f2b(wout1[t * 16384 + k * 128 + n]); return; }
    idx -= 3 * 16384;
    if (idx < 3 * 16384) { int t = idx / 16384, j = idx % 16384; int n = j >> 7, k = j & 127;
        wout2T[idx] = f2b(wout2[t * 16384 + k * 128 + n]); return; }
    idx -= 3 * 16384;
    if (idx < 64 * 128) { int n = idx >> 7, k = idx & 127;
        wa1T[idx] = f2b(wa1[k * 64 + n]); return; }
}

// ---------------------------------------------------------------------------
// CSR build (once per launch; edge list is constant across t)
__global__ __launch_bounds__(256) void k_zero(int* __restrict__ p, int n) {
    int i = blockIdx.x * 256 + threadIdx.x;
    if (i < n) p[i] = 0;
}

__global__ __launch_bounds__(256) void k_count(const int* __restrict__ a,
                                               int* __restrict__ counts) {
    int e = blockIdx.x * 256 + threadIdx.x;
    atomicAdd(&counts[a[2 * e]], 1);
    atomicAdd(&counts[a[2 * e + 1]], 1);
}

// single block: exclusive prefix sum of counts[N_ATOMS] -> ptr; cursor = ptr copy
__global__ __launch_bounds__(256) void k_scan(int* __restrict__ counts,
                                              int* __restrict__ ptr) {
    __shared__ int part[256];
    int tid = threadIdx.x;
    const int CH = N_ATOMS / 256;  // 512
    int base = tid * CH;
    int s = 0;
    for (int i = 0; i < CH; i++) s += counts[base + i];
    part[tid] = s;
    __syncthreads();
    if (tid == 0) {
        int acc = 0;
        for (int i = 0; i < 256; i++) { int v = part[i]; part[i] = acc; acc += v; }
    }
    __syncthreads();
    int run = part[tid];
    for (int i = 0; i < CH; i++) {
        int v = counts[base + i];
        ptr[base + i] = run;
        counts[base + i] = run;   // counts buffer becomes the fill cursor
        run += v;
    }
    if (tid == 255) ptr[N_ATOMS] = run;  // == 2E
}

__global__ __launch_bounds__(256) void k_fill(const int* __restrict__ a,
                                              int* __restrict__ cursor,
                                              int* __restrict__ adj) {
    int e = blockIdx.x * 256 + threadIdx.x;
    int A0 = a[2 * e], A1 = a[2 * e + 1];
    int p0 = atomicAdd(&cursor[A0], 1);
    adj[2 * p0] = e; adj[2 * p0 + 1] = A1;
    int p1 = atomicAdd(&cursor[A1], 1);
    adj[2 * p1] = e; adj[2 * p1 + 1] = A0;
}

// ---------------------------------------------------------------------------
// h = bf16(r) @ win[t]; (fallback also zeroes y)
__global__ __launch_bounds__(256) void k_h(const float* __restrict__ r,
                                           const bf16* __restrict__ winT_t,
                                           bf16* __restrict__ h,
                                           float* __restrict__ y) {
    __shared__ __align__(16) bf16 A[128][136];
    __shared__ __align__(16) bf16 B[128][72];
    int tid = threadIdx.x, n0 = blockIdx.x * 128;
    for (int idx = tid; idx < 128 * 128; idx += 256) {
        int row = idx >> 7, col = idx & 127;
        A[row][col] = f2b(r[(n0 + row) * DD + col]);
        if (y) y[(n0 + row) * FF + col] = 0.f;
    }
    stage_b(&B[0][0], winT_t, 0, 128, 128, tid);
    __syncthreads();
    int wave = tid >> 6, lane = tid & 63, q = lane >> 4, ln = lane & 15;
    floatx4 acc[2][8];
#pragma unroll
    for (int i = 0; i < 2; i++)
#pragma unroll
        for (int j = 0; j < 8; j++) acc[i][j] = (floatx4){0.f, 0.f, 0.f, 0.f};
    mfma_half<8>(&A[0][0], &B[0][0], acc, 0, wave, q, ln);
    __syncthreads();
    stage_b(&B[0][0], winT_t, 64, 128, 128, tid);
    __syncthreads();
    mfma_half<8>(&A[0][0], &B[0][0], acc, 64, wave, q, ln);
#pragma unroll
    for (int rt = 0; rt < 2; rt++)
#pragma unroll
        for (int ct = 0; ct < 8; ct++)
#pragma unroll
            for (int rg = 0; rg < 4; rg++) {
                int row = wave * 32 + rt * 16 + q * 4 + rg, col = ct * 16 + ln;
                h[(n0 + row) * FF + col] = f2b(acc[rt][ct][rg]);
            }
}

// edge filter only: Wc = bf16( (ssp(g@fw1+b1)@fw2 + b2) * C ) -> Wt[E][128]
__global__ __launch_bounds__(256) void k_edge_w(const float* __restrict__ dArr,
                                                const float* __restrict__ cArr,
                                                const bf16* __restrict__ fw1T_t,
                                                const float* __restrict__ fb1_t,
                                                const bf16* __restrict__ fw2T_t,
                                                const float* __restrict__ fb2_t,
                                                bf16* __restrict__ Wt) {
    __shared__ __align__(16) bf16 A[128][136];
    __shared__ __align__(16) bf16 B[128][72];
    __shared__ float dS[128], cS[128], b1S[128], b2S[128];
    int tid = threadIdx.x, e0 = blockIdx.x * 128;
    if (tid < 128) {
        int e = e0 + tid;
        dS[tid] = dArr[e];
        cS[tid] = cArr[e];
        b1S[tid] = fb1_t[tid];
        b2S[tid] = fb2_t[tid];
    }
    stage_b(&B[0][0], fw1T_t, 0, 128, 64, tid);
    __syncthreads();
    const float width = 5.0f / 49.0f;
    const float coeff = -0.5f / (width * width);
    for (int idx = tid; idx < 128 * 64; idx += 256) {
        int i = idx >> 6, k = idx & 63;
        float v = 0.f;
        if (k < GG) { float t = dS[i] - (float)k * width; v = __expf(coeff * t * t); }
        A[i][k] = f2b(v);
    }
    __syncthreads();
    int wave = tid >> 6, lane = tid & 63, q = lane >> 4, ln = lane & 15;
    floatx4 acc[2][8];
#pragma unroll
    for (int i = 0; i < 2; i++)
#pragma unroll
        for (int j = 0; j < 8; j++) acc[i][j] = (floatx4){0.f, 0.f, 0.f, 0.f};
    mfma_half<8>(&A[0][0], &B[0][0], acc, 0, wave, q, ln);   // K=64 (padded)
#pragma unroll
    for (int rt = 0; rt < 2; rt++)
#pragma unroll
        for (int ct = 0; ct < 8; ct++)
#pragma unroll
            for (int rg = 0; rg < 4; rg++) {
                int row = wave * 32 + rt * 16 + q * 4 + rg, col = ct * 16 + ln;
                A[row][col] = f2b(sspf(acc[rt][ct][rg] + b1S[col]));
            }
    __syncthreads();
    stage_b(&B[0][0], fw2T_t, 0, 128, 128, tid);
    __syncthreads();
#pragma unroll
    for (int i = 0; i < 2; i++)
#pragma unroll
        for (int j = 0; j < 8; j++) acc[i][j] = (floatx4){0.f, 0.f, 0.f, 0.f};
    mfma_half<8>(&A[0][0], &B[0][0], acc, 0, wave, q, ln);
    __syncthreads();
    stage_b(&B[0][0], fw2T_t, 64, 128, 128, tid);
    __syncthreads();
    mfma_half<8>(&A[0][0], &B[0][0], acc, 64, wave, q, ln);
    // Wc -> A tile (own wave rows; in-order within wave, rows disjoint across waves)
#pragma unroll
    for (int rt = 0; rt < 2; rt++)
#pragma unroll
        for (int ct = 0; ct < 8; ct++)
#pragma unroll
            for (int rg = 0; rg < 4; rg++) {
                int row = wave * 32 + rt * 16 + q * 4 + rg, col = ct * 16 + ln;
                A[row][col] = f2b((acc[rt][ct][rg] + b2S[col]) * cS[row]);
            }
    __syncthreads();
    // coalesced 16B store of the tile
    for (int i = tid; i < 128 * 16; i += 256) {
        int row = i >> 4, seg = i & 15;
        *(uint4*)(Wt + (size_t)(e0 + row) * FF + seg * 8) =
            *(const uint4*)(&A[row][seg * 8]);
    }
}

// pull-gather y rows (fp32 regs) straight into node-MLP A tile, then dr GEMMs, r+=dr
__global__ __launch_bounds__(256) void k_gather_node(const int* __restrict__ ptr,
                                                     const int* __restrict__ adj,
                                                     const bf16* __restrict__ Wt,
                                                     const bf16* __restrict__ h,
                                                     const bf16* __restrict__ wout1T_t,
                                                     const float* __restrict__ bo1_t,
                                                     const bf16* __restrict__ wout2T_t,
                                                     const float* __restrict__ bo2_t,
                                                     float* __restrict__ r) {
    __shared__ __align__(16) bf16 A[128][136];
    __shared__ __align__(16) bf16 B[128][72];
    __shared__ float b1S[128], b2S[128];
    int tid = threadIdx.x, n0 = blockIdx.x * 128;
    if (tid < 128) { b1S[tid] = bo1_t[tid]; b2S[tid] = bo2_t[tid]; }
    int wave = tid >> 6, lane = tid & 63;
    // gather: wave handles rows [wave*32, wave*32+32); lane owns cols 2l, 2l+1
    for (int k = 0; k < 32; k++) {
        int atom = n0 + wave * 32 + k;
        int beg = ptr[atom], end = ptr[atom + 1];
        float ax = 0.f, ay = 0.f;
        for (int base = beg; base < end; base += 64) {
            int deg = min(64, end - base);
            int eI = 0, oI = 0;
            if (lane < deg) {
                eI = adj[2 * (base + lane)];
                oI = adj[2 * (base + lane) + 1];
            }
            for (int j = 0; j < deg; j += 4) {
                unsigned int wp[4] = {0, 0, 0, 0}, hp[4] = {0, 0, 0, 0};
                int m = min(4, deg - j);
#pragma unroll
                for (int u = 0; u < 4; u++) {
                    if (u < m) {
                        int e  = __shfl(eI, j + u);
                        int ot = __shfl(oI, j + u);
                        wp[u] = *(const unsigned int*)(Wt + (size_t)e * FF + lane * 2);
                        hp[u] = *(const unsigned int*)(h + (size_t)ot * FF + lane * 2);
                    }
                }
#pragma unroll
                for (int u = 0; u < 4; u++)
                    if (u < m) {
                        float2 wf = up2(wp[u]), hf = up2(hp[u]);
                        ax = fmaf(wf.x, hf.x, ax);
                        ay = fmaf(wf.y, hf.y, ay);
                    }
            }
        }
        A[wave * 32 + k][lane * 2]     = f2b(ax);
        A[wave * 32 + k][lane * 2 + 1] = f2b(ay);
    }
    stage_b(&B[0][0], wout1T_t, 0, 128, 128, tid);
    __syncthreads();
    int q = lane >> 4, ln = lane & 15;
    floatx4 acc[2][8];
#pragma unroll
    for (int i = 0; i < 2; i++)
#pragma unroll
        for (int j = 0; j < 8; j++) acc[i][j] = (floatx4){0.f, 0.f, 0.f, 0.f};
    mfma_half<8>(&A[0][0], &B[0][0], acc, 0, wave, q, ln);
    __syncthreads();
    stage_b(&B[0][0], wout1T_t, 64, 128, 128, tid);
    __syncthreads();
    mfma_half<8>(&A[0][0], &B[0][0], acc, 64, wave, q, ln);
#pragma unroll
    for (int rt = 0; rt < 2; rt++)
#pragma unroll
        for (int ct = 0; ct < 8; ct++)
#pragma unroll
            for (int rg = 0; rg < 4; rg++) {
                int row = wave * 32 + rt * 16 + q * 4 + rg, col = ct * 16 + ln;
                A[row][col] = f2b(sspf(acc[rt][ct][rg] + b1S[col]));
            }
    __syncthreads();
    stage_b(&B[0][0], wout2T_t, 0, 128, 128, tid);
    __syncthreads();
#pragma unroll
    for (int i = 0; i < 2; i++)
#pragma unroll
        for (int j = 0; j < 8; j++) acc[i][j] = (floatx4){0.f, 0.f, 0.f, 0.f};
    mfma_half<8>(&A[0][0], &B[0][0], acc, 0, wave, q, ln);
    __syncthreads();
    stage_b(&B[0][0], wout2T_t, 64, 128, 128, tid);
    __syncthreads();
    mfma_half<8>(&A[0][0], &B[0][0], acc, 64, wave, q, ln);
#pragma unroll
    for (int rt = 0; rt < 2; rt++)
#pragma unroll
        for (int ct = 0; ct < 8; ct++)
#pragma unroll
            for (int rg = 0; rg < 4; rg++) {
                int row = wave * 32 + rt * 16 + q * 4 + rg, col = ct * 16 + ln;
                int off = (n0 + row) * DD + col;
                r[off] += acc[rt][ct][rg] + b2S[col];
            }
}

// ---------------------------------------------------------------------------
// fallback kernels (round-2 verified path): atomic scatter + separate k_node
__global__ __launch_bounds__(256) void k_edge(const float* __restrict__ dArr,
                                              const float* __restrict__ cArr,
                                              const int* __restrict__ a,
                                              const bf16* __restrict__ fw1T_t,
                                              const float* __restrict__ fb1_t,
                                              const bf16* __restrict__ fw2T_t,
                                              const float* __restrict__ fb2_t,
                                              const bf16* __restrict__ h,
                                              float* __restrict__ y) {
    __shared__ __align__(16) bf16 A[128][136];
    __shared__ __align__(16) bf16 B[128][72];
    __shared__ float dS[128], cS[128], b1S[128], b2S[128];
    __shared__ int a0S[128], a1S[128];
    int tid = threadIdx.x, e0 = blockIdx.x * 128;
    if (tid < 128) {
        int e = e0 + tid;
        dS[tid] = dArr[e]; cS[tid] = cArr[e];
        a0S[tid] = a[2 * e]; a1S[tid] = a[2 * e + 1];
        b1S[tid] = fb1_t[tid]; b2S[tid] = fb2_t[tid];
    }
    stage_b(&B[0][0], fw1T_t, 0, 128, 64, tid);
    __syncthreads();
    const float width = 5.0f / 49.0f;
    const float coeff = -0.5f / (width * width);
    for (int idx = tid; idx < 128 * 64; idx += 256) {
        int i = idx >> 6, k = idx & 63;
        float v = 0.f;
        if (k < GG) { float t = dS[i] - (float)k * width; v = __expf(coeff * t * t); }
        A[i][k] = f2b(v);
    }
    __syncthreads();
    int wave = tid >> 6, lane = tid & 63, q = lane >> 4, ln = lane & 15;
    floatx4 acc[2][8];
#pragma unroll
    for (int i = 0; i < 2; i++)
#pragma unroll
        for (int j = 0; j < 8; j++) acc[i][j] = (floatx4){0.f, 0.f, 0.f, 0.f};
    mfma_half<8>(&A[0][0], &B[0][0], acc, 0, wave, q, ln);
#pragma unroll
    for (int rt = 0; rt < 2; rt++)
#pragma unroll
        for (int ct = 0; ct < 8; ct++)
#pragma unroll
            for (int rg = 0; rg < 4; rg++) {
                int row = wave * 32 + rt * 16 + q * 4 + rg, col = ct * 16 + ln;
                A[row][col] = f2b(sspf(acc[rt][ct][rg] + b1S[col]));
            }
    __syncthreads();
    stage_b(&B[0][0], fw2T_t, 0, 128, 128, tid);
    __syncthreads();
#pragma unroll
    for (int i = 0; i < 2; i++)
#pragma unroll
        for (int j = 0; j < 8; j++) acc[i][j] = (floatx4){0.f, 0.f, 0.f, 0.f};
    mfma_half<8>(&A[0][0], &B[0][0], acc, 0, wave, q, ln);
    __syncthreads();
    stage_b(&B[0][0], fw2T_t, 64, 128, 128, tid);
    __syncthreads();
    mfma_half<8>(&A[0][0], &B[0][0], acc, 64, wave, q, ln);
#pragma unroll
    for (int rt = 0; rt < 2; rt++)
#pragma unroll
        for (int ct = 0; ct < 8; ct++)
#pragma unroll
            for (int rg = 0; rg < 4; rg++) {
                int row = wave * 32 + rt * 16 + q * 4 + rg, col = ct * 16 + ln;
                float w = (acc[rt][ct][rg] + b2S[col]) * cS[row];
                int A0 = a0S[row], A1 = a1S[row];
                float h0 = b2f(h[A0 * FF + col]);
                float h1 = b2f(h[A1 * FF + col]);
                atomicAdd(&y[A0 * FF + col], h1 * w);
                atomicAdd(&y[A1 * FF + col], h0 * w);
            }
}

__global__ __launch_bounds__(256) void k_node(const float* __restrict__ y,
                                              const bf16* __restrict__ wout1T_t,
                                              const float* __restrict__ bo1_t,
                                              const bf16* __restrict__ wout2T_t,
                                              const float* __restrict__ bo2_t,
                                              float* __restrict__ r) {
    __shared__ __align__(16) bf16 A[128][136];
    __shared__ __align__(16) bf16 B[128][72];
    __shared__ float b1S[128], b2S[128];
    int tid = threadIdx.x, n0 = blockIdx.x * 128;
    if (tid < 128) { b1S[tid] = bo1_t[tid]; b2S[tid] = bo2_t[tid]; }
    for (int idx = tid; idx < 128 * 128; idx += 256) {
        int row = idx >> 7, col = idx & 127;
        A[row][col] = f2b(y[(n0 + row) * FF + col]);
    }
    stage_b(&B[0][0], wout1T_t, 0, 128, 128, tid);
    __syncthreads();
    int wave = tid >> 6, lane = tid & 63, q = lane >> 4, ln = lane & 15;
    floatx4 acc[2][8];
#pragma unroll
    for (int i = 0; i < 2; i++)
#pragma unroll
        for (int j = 0; j < 8; j++) acc[i][j] = (floatx4){0.f, 0.f, 0.f, 0.f};
    mfma_half<8>(&A[0][0], &B[0][0], acc, 0, wave, q, ln);
    __syncthreads();
    stage_b(&B[0][0], wout1T_t, 64, 128, 128, tid);
    __syncthreads();
    mfma_half<8>(&A[0][0], &B[0][0], acc, 64, wave, q, ln);
#pragma unroll
    for (int rt = 0; rt < 2; rt++)
#pragma unroll
        for (int ct = 0; ct < 8; ct++)
#pragma unroll
            for (int rg = 0; rg < 4; rg++) {
                int row = wave * 32 + rt * 16 + q * 4 + rg, col = ct * 16 + ln;
                A[row][col] = f2b(sspf(acc[rt][ct][rg] + b1S[col]));
            }
    __syncthreads();
    stage_b(&B[0][0], wout2T_t, 0, 128, 128, tid);
    __syncthreads();
#pragma unroll
    for (int i = 0; i < 2; i++)
#pragma unroll
        for (int j = 0; j < 8; j++) acc[i][j] = (floatx4){0.f, 0.f, 0.f, 0.f};
    mfma_half<8>(&A[0][0], &B[0][0], acc, 0, wave, q, ln);
    __syncthreads();
    stage_b(&B[0][0], wout2T_t, 64, 128, 128, tid);
    __syncthreads();
    mfma_half<8>(&A[0][0], &B[0][0], acc, 64, wave, q, ln);
#pragma unroll
    for (int rt = 0; rt < 2; rt++)
#pragma unroll
        for (int ct = 0; ct < 8; ct++)
#pragma unroll
            for (int rg = 0; rg < 4; rg++) {
                int row = wave * 32 + rt * 16 + q * 4 + rg, col = ct * 16 + ln;
                int off = (n0 + row) * DD + col;
                r[off] += acc[rt][ct][rg] + b2S[col];
            }
}

// ---------------------------------------------------------------------------
__global__ __launch_bounds__(256) void k_head(const float* __restrict__ r,
                                              const bf16* __restrict__ wa1T,
                                              const float* __restrict__ ba1,
                                              const float* __restrict__ wa2,
                                              const float* __restrict__ ba2,
                                              const int* __restrict__ mol,
                                              float* __restrict__ molE) {
    __shared__ __align__(16) bf16 A[128][136];
    __shared__ __align__(16) bf16 B[64][72];
    __shared__ __align__(16) bf16 U[128][72];
    __shared__ float wa2S[64], ba1S[64];
    int tid = threadIdx.x, n0 = blockIdx.x * 128;
    if (tid < 64) { wa2S[tid] = wa2[tid]; ba1S[tid] = ba1[tid]; }
    for (int idx = tid; idx < 128 * 128; idx += 256) {
        int row = idx >> 7, col = idx & 127;
        A[row][col] = f2b(r[(n0 + row) * DD + col]);
    }
    stage_b(&B[0][0], wa1T, 0, 64, 128, tid);
    __syncthreads();
    int wave = tid >> 6, lane = tid & 63, q = lane >> 4, ln = lane & 15;
    floatx4 acc[2][4];
#pragma unroll
    for (int i = 0; i < 2; i++)
#pragma unroll
        for (int j = 0; j < 4; j++) acc[i][j] = (floatx4){0.f, 0.f, 0.f, 0.f};
    mfma_half<4>(&A[0][0], &B[0][0], acc, 0, wave, q, ln);
    __syncthreads();
    stage_b(&B[0][0], wa1T, 64, 64, 128, tid);
    __syncthreads();
    mfma_half<4>(&A[0][0], &B[0][0], acc, 64, wave, q, ln);
#pragma unroll
    for (int rt = 0; rt < 2; rt++)
#pragma unroll
        for (int ct = 0; ct < 4; ct++)
#pragma unroll
            for (int rg = 0; rg < 4; rg++) {
                int row = wave * 32 + rt * 16 + q * 4 + rg, col = ct * 16 + ln;
                U[row][col] = f2b(acc[rt][ct][rg] + ba1S[col]);
            }
    __syncthreads();
    if (tid < 128) {
        float s = ba2[0];
#pragma unroll
        for (int j = 0; j < 64; j++) s += sspf(b2f(U[tid][j])) * wa2S[j];
        atomicAdd(&molE[mol[n0 + tid]], s);
    }
}

__global__ __launch_bounds__(256) void k_out(const float* __restrict__ molE,
                                             float* __restrict__ out) {
    int i = blockIdx.x * 256 + threadIdx.x;
    out[i] = molE[i];
}

// ---------------------------------------------------------------------------
extern "C" void kernel_launch(void* const* d_in, const int* in_sizes, int n_in,
                              void* d_out, int out_size, void* d_ws, size_t ws_size,
                              hipStream_t stream) {
    const float* xyz   = (const float*)d_in[0];
    const float* emb   = (const float*)d_in[1];
    const float* fw1   = (const float*)d_in[2];
    const float* fb1   = (const float*)d_in[3];
    const float* fw2   = (const float*)d_in[4];
    const float* fb2   = (const float*)d_in[5];
    const float* win   = (const float*)d_in[6];
    const float* wout1 = (const float*)d_in[7];
    const float* bout1 = (const float*)d_in[8];
    const float* wout2 = (const float*)d_in[9];
    const float* bout2 = (const float*)d_in[10];
    const float* wa1   = (const float*)d_in[11];
    const float* ba1   = (const float*)d_in[12];
    const float* wa2   = (const float*)d_in[13];
    const float* ba2   = (const float*)d_in[14];
    const int*  z     = (const int*)d_in[15];
    const int*  a     = (const int*)d_in[16];
    const int*  mol   = (const int*)d_in[17];

    char* ws = (char*)d_ws;
    float* r    = (float*)ws; ws += (size_t)N_ATOMS * DD * 4;   // 67,108,864
    bf16*  h    = (bf16*) ws; ws += (size_t)N_ATOMS * FF * 2;   // 33,554,432
    float* dA   = (float*)ws; ws += (size_t)N_EDGES * 4;        //  2,097,152
    float* cA   = (float*)ws; ws += (size_t)N_EDGES * 4;        //  2,097,152
    float* molE = (float*)ws; ws += (size_t)N_MOLS * 4;         //      8,192
    bf16*  fw1T   = (bf16*)ws; ws += 3 * 128 * 64 * 2;          //     49,152
    bf16*  fw2T   = (bf16*)ws; ws += 3 * 128 * 128 * 2;         //     98,304
    bf16*  winT   = (bf16*)ws; ws += 3 * 128 * 128 * 2;
    bf16*  wout1T = (bf16*)ws; ws += 3 * 128 * 128 * 2;
    bf16*  wout2T = (bf16*)ws; ws += 3 * 128 * 128 * 2;
    bf16*  wa1T   = (bf16*)ws; ws += 64 * 128 * 2;              //     16,384
    int*   ptr    = (int*)ws;  ws += 524304;                    // N_ATOMS+1 ints, padded
    int*   cursor = (int*)ws;  ws += (size_t)N_ATOMS * 4;       //    524,288
    int*   adj    = (int*)ws;  ws += (size_t)2 * N_EDGES * 2 * 4; // 8,388,608
    bf16*  Wt     = (bf16*)ws; ws += (size_t)N_EDGES * FF * 2;  // 134,217,728
    size_t need = (size_t)(ws - (char*)d_ws);                   // 248,979,472

    k_init<<<N_ATOMS * DD / 256, 256, 0, stream>>>(emb, z, r);
    k_dist<<<N_EDGES / 256, 256, 0, stream>>>(xyz, a, dA, cA, molE);
    k_wt<<<896, 256, 0, stream>>>(fw1, fw2, win, wout1, wout2, wa1,
                                  fw1T, fw2T, winT, wout1T, wout2T, wa1T);

    if (ws_size >= need) {
        // CSR build (edge list constant across t)
        k_zero<<<(N_ATOMS + 255) / 256, 256, 0, stream>>>(cursor, N_ATOMS);
        k_count<<<N_EDGES / 256, 256, 0, stream>>>(a, cursor);
        k_scan<<<1, 256, 0, stream>>>(cursor, ptr);
        k_fill<<<N_EDGES / 256, 256, 0, stream>>>(a, cursor, adj);
        for (int t = 0; t < TT; t++) {
            k_h<<<N_ATOMS / 128, 256, 0, stream>>>(r, winT + t * 16384, h, nullptr);
            k_edge_w<<<N_EDGES / 128, 256, 0, stream>>>(dA, cA,
                                                        fw1T + t * 8192, fb1 + t * FF,
                                                        fw2T + t * 16384, fb2 + t * FF, Wt);
            k_gather_node<<<N_ATOMS / 128, 256, 0, stream>>>(ptr, adj, Wt, h,
                                                             wout1T + t * 16384, bout1 + t * DD,
                                                             wout2T + t * 16384, bout2 + t * DD, r);
        }
    } else {
        // fallback: round-2 verified atomic-scatter path (reuse CSR space as y)
        float* y = (float*)ptr;  // needs N_ATOMS*FF*4 = 67 MB; fits: round-2 total was ~172 MB
        for (int t = 0; t < TT; t++) {
            k_h<<<N_ATOMS / 128, 256, 0, stream>>>(r, winT + t * 16384, h, y);
            k_edge<<<N_EDGES / 128, 256, 0, stream>>>(dA, cA, a,
                                                      fw1T + t * 8192, fb1 + t * FF,
                                                      fw2T + t * 16384, fb2 + t * FF, h, y);
            k_node<<<N_ATOMS / 128, 256, 0, stream>>>(y, wout1T + t * 16384, bout1 + t * DD,
                                                      wout2T + t * 16384, bout2 + t * DD, r);
        }
    }
    k_head<<<N_ATOMS / 128, 256, 0, stream>>>(r, wa1T, ba1, wa2, ba2, mol, molE);
    k_out<<<N_MOLS / 256, 256, 0, stream>>>(molE, (float*)d_out);
}

// Round 4
// 2011.715 us; speedup vs baseline: 1.1011x; 1.1011x over previous
//
#include <hip/hip_runtime.h>
#include <hip/hip_bf16.h>

#define N_ATOMS 131072
#define N_EDGES 524288
#define N_MOLS  2048
#define DD      128   // n_atom_basis
#define FF      128   // n_filters
#define GG      50    // n_gaussians
#define TT      3

typedef __hip_bfloat16 bf16;
typedef __attribute__((ext_vector_type(8))) short short8;
typedef __attribute__((ext_vector_type(4))) float floatx4;

__device__ __forceinline__ float b2f(bf16 v) { return __bfloat162float(v); }
__device__ __forceinline__ bf16  f2b(float v) { return __float2bfloat16(v); }

// unpack two bf16 (packed in a uint, low half = lower address) to float2
__device__ __forceinline__ float2 up2(unsigned int u) {
    float2 f;
    f.x = __uint_as_float(u << 16);
    f.y = __uint_as_float(u & 0xffff0000u);
    return f;
}

__device__ __forceinline__ unsigned short b2us(bf16 v) {
    union { bf16 b; unsigned short u; } c; c.b = v; return c.u;
}

// packed bf16x2 multiply: (w0*h0, w1*h1) rounded to bf16
__device__ __forceinline__ unsigned int pkmul(unsigned int wa, unsigned int hb) {
    float2 w = up2(wa), h = up2(hb);
    return ((unsigned int)b2us(f2b(w.y * h.y)) << 16) | b2us(f2b(w.x * h.x));
}

// shifted softplus: softplus(x) - ln2, numerically stable
__device__ __forceinline__ float sspf(float x) {
    return fmaxf(x, 0.f) + log1pf(__expf(-fabsf(x))) - 0.69314718056f;
}

// ---------------------------------------------------------------------------
// MFMA helpers.  A tile: [128 rows][136] bf16 LDS (stride 136).
// B tile: [n][72] bf16 LDS holding B^T chunk: B[n][kk], kk<64.
// Block = 256 threads = 4 waves; wave w owns output rows [32w, 32w+32).
// 16x16x32 bf16 layouts: A[m=lane&15][k=q*8+j], B[k=q*8+j][n=lane&15],
// D[row=q*4+reg][col=lane&15].  (verified, learn_hip m89)
// ---------------------------------------------------------------------------
template <int NCT>
__device__ __forceinline__ void mfma_half(const bf16* A, const bf16* B,
                                          floatx4 (&acc)[2][NCT],
                                          int kA, int wave, int q, int ln) {
#pragma unroll
    for (int k0 = 0; k0 < 64; k0 += 32) {
        short8 a0 = *(const short8*)(A + (wave * 32 + ln) * 136 + kA + k0 + q * 8);
        short8 a1 = *(const short8*)(A + (wave * 32 + 16 + ln) * 136 + kA + k0 + q * 8);
#pragma unroll
        for (int ct = 0; ct < NCT; ct++) {
            short8 b = *(const short8*)(B + (ct * 16 + ln) * 72 + k0 + q * 8);
            acc[0][ct] = __builtin_amdgcn_mfma_f32_16x16x32_bf16(a0, b, acc[0][ct], 0, 0, 0);
            acc[1][ct] = __builtin_amdgcn_mfma_f32_16x16x32_bf16(a1, b, acc[1][ct], 0, 0, 0);
        }
    }
}

__device__ __forceinline__ void stage_b(bf16* B, const bf16* WT, int k0,
                                        int nrows, int ldk, int tid) {
    for (int i = tid; i < nrows * 8; i += 256) {
        int n = i >> 3, kc = i & 7;
        *(short8*)(B + n * 72 + kc * 8) =
            *(const short8*)(WT + n * ldk + k0 + kc * 8);
    }
}

// ---------------------------------------------------------------------------
__global__ __launch_bounds__(256) void k_init(const float* __restrict__ emb,
                                              const int* __restrict__ z,
                                              float* __restrict__ r) {
    int idx = blockIdx.x * 256 + threadIdx.x;
    int atom = idx >> 7, col = idx & 127;
    r[idx] = emb[z[atom] * DD + col];
}

__global__ __launch_bounds__(256) void k_dist(const float* __restrict__ xyz,
                                              const int* __restrict__ a,
                                              float* __restrict__ dArr,
                                              float* __restrict__ cArr,
                                              float* __restrict__ molE) {
    int e = blockIdx.x * 256 + threadIdx.x;
    if (e < N_MOLS) molE[e] = 0.f;
    int A0 = a[2 * e], A1 = a[2 * e + 1];
    float dx = xyz[3 * A0]     - xyz[3 * A1];
    float dy = xyz[3 * A0 + 1] - xyz[3 * A1 + 1];
    float dz = xyz[3 * A0 + 2] - xyz[3 * A1 + 2];
    float d = sqrtf(dx * dx + dy * dy + dz * dz);
    dArr[e] = d;
    cArr[e] = 0.5f * (__cosf(d * 0.6283185307179586f) + 1.f);
}

__global__ __launch_bounds__(256) void k_wt(const float* __restrict__ fw1,
                                            const float* __restrict__ fw2,
                                            const float* __restrict__ win,
                                            const float* __restrict__ wout1,
                                            const float* __restrict__ wout2,
                                            const float* __restrict__ wa1,
                                            bf16* __restrict__ fw1T, bf16* __restrict__ fw2T,
                                            bf16* __restrict__ winT, bf16* __restrict__ wout1T,
                                            bf16* __restrict__ wout2T, bf16* __restrict__ wa1T) {
    int idx = blockIdx.x * 256 + threadIdx.x;
    if (idx < 3 * 128 * 64) {
        int t = idx / 8192, j = idx % 8192;
        int n = j >> 6, k = j & 63;
        fw1T[idx] = (k < GG) ? f2b(fw1[t * GG * FF + k * FF + n]) : f2b(0.f);
        return;
    }
    idx -= 3 * 128 * 64;
    if (idx < 3 * 16384) { int t = idx / 16384, j = idx % 16384; int n = j >> 7, k = j & 127;
        fw2T[idx] = f2b(fw2[t * 16384 + k * 128 + n]); return; }
    idx -= 3 * 16384;
    if (idx < 3 * 16384) { int t = idx / 16384, j = idx % 16384; int n = j >> 7, k = j & 127;
        winT[idx] = f2b(win[t * 16384 + k * 128 + n]); return; }
    idx -= 3 * 16384;
    if (idx < 3 * 16384) { int t = idx / 16384, j = idx % 16384; int n = j >> 7, k = j & 127;
        wout1T[idx] = f2b(wout1[t * 16384 + k * 128 + n]); return; }
    idx -= 3 * 16384;
    if (idx < 3 * 16384) { int t = idx / 16384, j = idx % 16384; int n = j >> 7, k = j & 127;
        wout2T[idx] = f2b(wout2[t * 16384 + k * 128 + n]); return; }
    idx -= 3 * 16384;
    if (idx < 64 * 128) { int n = idx >> 7, k = idx & 127;
        wa1T[idx] = f2b(wa1[k * 64 + n]); return; }
}

// ---------------------------------------------------------------------------
// CSR build (once per launch; edge list is constant across t)
__global__ __launch_bounds__(256) void k_zero(int* __restrict__ p, int n) {
    int i = blockIdx.x * 256 + threadIdx.x;
    if (i < n) p[i] = 0;
}

__global__ __launch_bounds__(256) void k_count(const int* __restrict__ a,
                                               int* __restrict__ counts) {
    int e = blockIdx.x * 256 + threadIdx.x;
    atomicAdd(&counts[a[2 * e]], 1);
    atomicAdd(&counts[a[2 * e + 1]], 1);
}

// single block: exclusive prefix sum of counts[N_ATOMS] -> ptr; cursor = ptr copy
__global__ __launch_bounds__(256) void k_scan(int* __restrict__ counts,
                                              int* __restrict__ ptr) {
    __shared__ int part[256];
    int tid = threadIdx.x;
    const int CH = N_ATOMS / 256;  // 512
    int base = tid * CH;
    int s = 0;
    for (int i = 0; i < CH; i++) s += counts[base + i];
    part[tid] = s;
    __syncthreads();
    if (tid == 0) {
        int acc = 0;
        for (int i = 0; i < 256; i++) { int v = part[i]; part[i] = acc; acc += v; }
    }
    __syncthreads();
    int run = part[tid];
    for (int i = 0; i < CH; i++) {
        int v = counts[base + i];
        ptr[base + i] = run;
        counts[base + i] = run;   // counts buffer becomes the fill cursor
        run += v;
    }
    if (tid == 255) ptr[N_ATOMS] = run;  // == 2E
}

// slot assignment: eslot[2e] = slot of edge e in a0's segment, eslot[2e+1] in a1's
__global__ __launch_bounds__(256) void k_fill(const int* __restrict__ a,
                                              int* __restrict__ cursor,
                                              int* __restrict__ eslot) {
    int e = blockIdx.x * 256 + threadIdx.x;
    int A0 = a[2 * e], A1 = a[2 * e + 1];
    eslot[2 * e]     = atomicAdd(&cursor[A0], 1);
    eslot[2 * e + 1] = atomicAdd(&cursor[A1], 1);
}

// ---------------------------------------------------------------------------
// h = bf16(r) @ win[t]; (fallback also zeroes y)
__global__ __launch_bounds__(256) void k_h(const float* __restrict__ r,
                                           const bf16* __restrict__ winT_t,
                                           bf16* __restrict__ h,
                                           float* __restrict__ y) {
    __shared__ __align__(16) bf16 A[128][136];
    __shared__ __align__(16) bf16 B[128][72];
    int tid = threadIdx.x, n0 = blockIdx.x * 128;
    for (int i = tid; i < 128 * 32; i += 256) {
        int row = i >> 5, c4 = (i & 31) * 4;
        float4 v = *(const float4*)(r + (size_t)(n0 + row) * DD + c4);
        A[row][c4]     = f2b(v.x);
        A[row][c4 + 1] = f2b(v.y);
        A[row][c4 + 2] = f2b(v.z);
        A[row][c4 + 3] = f2b(v.w);
        if (y) *(float4*)(y + (size_t)(n0 + row) * FF + c4) = (float4){0.f, 0.f, 0.f, 0.f};
    }
    stage_b(&B[0][0], winT_t, 0, 128, 128, tid);
    __syncthreads();
    int wave = tid >> 6, lane = tid & 63, q = lane >> 4, ln = lane & 15;
    floatx4 acc[2][8];
#pragma unroll
    for (int i = 0; i < 2; i++)
#pragma unroll
        for (int j = 0; j < 8; j++) acc[i][j] = (floatx4){0.f, 0.f, 0.f, 0.f};
    mfma_half<8>(&A[0][0], &B[0][0], acc, 0, wave, q, ln);
    __syncthreads();
    stage_b(&B[0][0], winT_t, 64, 128, 128, tid);
    __syncthreads();
    mfma_half<8>(&A[0][0], &B[0][0], acc, 64, wave, q, ln);
#pragma unroll
    for (int rt = 0; rt < 2; rt++)
#pragma unroll
        for (int ct = 0; ct < 8; ct++)
#pragma unroll
            for (int rg = 0; rg < 4; rg++) {
                int row = wave * 32 + rt * 16 + q * 4 + rg, col = ct * 16 + ln;
                h[(size_t)(n0 + row) * FF + col] = f2b(acc[rt][ct][rg]);
            }
}

// edge filter W = (ssp(g@fw1+b1)@fw2+b2)*C, then write both directed products
// bf16(W ⊙ h[other]) straight into CSR slot order: Pcsr[slot][128].
__global__ __launch_bounds__(256) void k_edge_w(const float* __restrict__ dArr,
                                                const float* __restrict__ cArr,
                                                const int* __restrict__ a,
                                                const int* __restrict__ eslot,
                                                const bf16* __restrict__ fw1T_t,
                                                const float* __restrict__ fb1_t,
                                                const bf16* __restrict__ fw2T_t,
                                                const float* __restrict__ fb2_t,
                                                const bf16* __restrict__ h,
                                                bf16* __restrict__ Pcsr) {
    __shared__ __align__(16) bf16 A[128][136];
    __shared__ __align__(16) bf16 B[128][72];
    __shared__ float dS[128], cS[128], b1S[128], b2S[128];
    __shared__ int a0S[128], a1S[128], p0S[128], p1S[128];
    int tid = threadIdx.x, e0 = blockIdx.x * 128;
    if (tid < 128) {
        int e = e0 + tid;
        dS[tid] = dArr[e];
        cS[tid] = cArr[e];
        b1S[tid] = fb1_t[tid];
        b2S[tid] = fb2_t[tid];
        a0S[tid] = a[2 * e];
        a1S[tid] = a[2 * e + 1];
        p0S[tid] = eslot[2 * e];
        p1S[tid] = eslot[2 * e + 1];
    }
    stage_b(&B[0][0], fw1T_t, 0, 128, 64, tid);
    __syncthreads();
    const float width = 5.0f / 49.0f;
    const float coeff = -0.5f / (width * width);
    for (int idx = tid; idx < 128 * 64; idx += 256) {
        int i = idx >> 6, k = idx & 63;
        float v = 0.f;
        if (k < GG) { float t = dS[i] - (float)k * width; v = __expf(coeff * t * t); }
        A[i][k] = f2b(v);
    }
    __syncthreads();
    int wave = tid >> 6, lane = tid & 63, q = lane >> 4, ln = lane & 15;
    floatx4 acc[2][8];
#pragma unroll
    for (int i = 0; i < 2; i++)
#pragma unroll
        for (int j = 0; j < 8; j++) acc[i][j] = (floatx4){0.f, 0.f, 0.f, 0.f};
    mfma_half<8>(&A[0][0], &B[0][0], acc, 0, wave, q, ln);   // K=64 (padded)
#pragma unroll
    for (int rt = 0; rt < 2; rt++)
#pragma unroll
        for (int ct = 0; ct < 8; ct++)
#pragma unroll
            for (int rg = 0; rg < 4; rg++) {
                int row = wave * 32 + rt * 16 + q * 4 + rg, col = ct * 16 + ln;
                A[row][col] = f2b(sspf(acc[rt][ct][rg] + b1S[col]));
            }
    __syncthreads();
    stage_b(&B[0][0], fw2T_t, 0, 128, 128, tid);
    __syncthreads();
#pragma unroll
    for (int i = 0; i < 2; i++)
#pragma unroll
        for (int j = 0; j < 8; j++) acc[i][j] = (floatx4){0.f, 0.f, 0.f, 0.f};
    mfma_half<8>(&A[0][0], &B[0][0], acc, 0, wave, q, ln);
    __syncthreads();
    stage_b(&B[0][0], fw2T_t, 64, 128, 128, tid);
    __syncthreads();
    mfma_half<8>(&A[0][0], &B[0][0], acc, 64, wave, q, ln);
    // W -> A tile (own wave rows; mfma_half only reads own-wave rows, no hazard)
#pragma unroll
    for (int rt = 0; rt < 2; rt++)
#pragma unroll
        for (int ct = 0; ct < 8; ct++)
#pragma unroll
            for (int rg = 0; rg < 4; rg++) {
                int row = wave * 32 + rt * 16 + q * 4 + rg, col = ct * 16 + ln;
                A[row][col] = f2b((acc[rt][ct][rg] + b2S[col]) * cS[row]);
            }
    __syncthreads();
    // product scatter: 256 directed rows x 16 segs of 8 bf16 (16B) each.
    // threads 0..15 cover one row's 256 B -> coalesced load of h row + store.
    for (int i = tid; i < 256 * 16; i += 256) {
        int drow = i >> 4, seg = i & 15;
        int er = drow >> 1;
        bool s0 = (drow & 1) == 0;
        int oA   = s0 ? a1S[er] : a0S[er];   // y[a0] += h[a1]*W ; y[a1] += h[a0]*W
        int slot = s0 ? p0S[er] : p1S[er];
        uint4 hv = *(const uint4*)(h + (size_t)oA * FF + seg * 8);
        uint4 wv = *(const uint4*)(&A[er][seg * 8]);
        uint4 o;
        o.x = pkmul(wv.x, hv.x);
        o.y = pkmul(wv.y, hv.y);
        o.z = pkmul(wv.z, hv.z);
        o.w = pkmul(wv.w, hv.w);
        *(uint4*)(Pcsr + (size_t)slot * FF + seg * 8) = o;
    }
}

// segmented sum of contiguous CSR product rows -> node MLP -> r += dr
__global__ __launch_bounds__(256) void k_seg_node(const int* __restrict__ ptr,
                                                  const bf16* __restrict__ Pcsr,
                                                  const bf16* __restrict__ wout1T_t,
                                                  const float* __restrict__ bo1_t,
                                                  const bf16* __restrict__ wout2T_t,
                                                  const float* __restrict__ bo2_t,
                                                  float* __restrict__ r) {
    __shared__ __align__(16) bf16 A[128][136];
    __shared__ __align__(16) bf16 B[128][72];
    __shared__ float b1S[128], b2S[128];
    int tid = threadIdx.x, n0 = blockIdx.x * 128;
    if (tid < 128) { b1S[tid] = bo1_t[tid]; b2S[tid] = bo2_t[tid]; }
    int wave = tid >> 6, lane = tid & 63;
    // wave handles atoms [wave*32, wave*32+32); lane owns cols 2l, 2l+1.
    // Rows for one atom are CONTIGUOUS -> pure streaming reads.
    for (int k = 0; k < 32; k++) {
        int atom = n0 + wave * 32 + k;
        int beg = ptr[atom], end = ptr[atom + 1];
        float ax = 0.f, ay = 0.f;
        int row = beg;
        for (; row + 4 <= end; row += 4) {
            unsigned int u0 = *(const unsigned int*)(Pcsr + (size_t)(row    ) * FF + lane * 2);
            unsigned int u1 = *(const unsigned int*)(Pcsr + (size_t)(row + 1) * FF + lane * 2);
            unsigned int u2 = *(const unsigned int*)(Pcsr + (size_t)(row + 2) * FF + lane * 2);
            unsigned int u3 = *(const unsigned int*)(Pcsr + (size_t)(row + 3) * FF + lane * 2);
            float2 f0 = up2(u0), f1 = up2(u1), f2v = up2(u2), f3 = up2(u3);
            ax += (f0.x + f1.x) + (f2v.x + f3.x);
            ay += (f0.y + f1.y) + (f2v.y + f3.y);
        }
        for (; row < end; row++) {
            float2 f = up2(*(const unsigned int*)(Pcsr + (size_t)row * FF + lane * 2));
            ax += f.x;
            ay += f.y;
        }
        A[wave * 32 + k][lane * 2]     = f2b(ax);
        A[wave * 32 + k][lane * 2 + 1] = f2b(ay);
    }
    stage_b(&B[0][0], wout1T_t, 0, 128, 128, tid);
    __syncthreads();
    int q = lane >> 4, ln = lane & 15;
    floatx4 acc[2][8];
#pragma unroll
    for (int i = 0; i < 2; i++)
#pragma unroll
        for (int j = 0; j < 8; j++) acc[i][j] = (floatx4){0.f, 0.f, 0.f, 0.f};
    mfma_half<8>(&A[0][0], &B[0][0], acc, 0, wave, q, ln);
    __syncthreads();
    stage_b(&B[0][0], wout1T_t, 64, 128, 128, tid);
    __syncthreads();
    mfma_half<8>(&A[0][0], &B[0][0], acc, 64, wave, q, ln);
#pragma unroll
    for (int rt = 0; rt < 2; rt++)
#pragma unroll
        for (int ct = 0; ct < 8; ct++)
#pragma unroll
            for (int rg = 0; rg < 4; rg++) {
                int row = wave * 32 + rt * 16 + q * 4 + rg, col = ct * 16 + ln;
                A[row][col] = f2b(sspf(acc[rt][ct][rg] + b1S[col]));
            }
    __syncthreads();
    stage_b(&B[0][0], wout2T_t, 0, 128, 128, tid);
    __syncthreads();
#pragma unroll
    for (int i = 0; i < 2; i++)
#pragma unroll
        for (int j = 0; j < 8; j++) acc[i][j] = (floatx4){0.f, 0.f, 0.f, 0.f};
    mfma_half<8>(&A[0][0], &B[0][0], acc, 0, wave, q, ln);
    __syncthreads();
    stage_b(&B[0][0], wout2T_t, 64, 128, 128, tid);
    __syncthreads();
    mfma_half<8>(&A[0][0], &B[0][0], acc, 64, wave, q, ln);
#pragma unroll
    for (int rt = 0; rt < 2; rt++)
#pragma unroll
        for (int ct = 0; ct < 8; ct++)
#pragma unroll
            for (int rg = 0; rg < 4; rg++) {
                int row = wave * 32 + rt * 16 + q * 4 + rg, col = ct * 16 + ln;
                size_t off = (size_t)(n0 + row) * DD + col;
                r[off] += acc[rt][ct][rg] + b2S[col];
            }
}

// ---------------------------------------------------------------------------
// fallback kernels (round-2 verified path): atomic scatter + separate k_node
__global__ __launch_bounds__(256) void k_edge(const float* __restrict__ dArr,
                                              const float* __restrict__ cArr,
                                              const int* __restrict__ a,
                                              const bf16* __restrict__ fw1T_t,
                                              const float* __restrict__ fb1_t,
                                              const bf16* __restrict__ fw2T_t,
                                              const float* __restrict__ fb2_t,
                                              const bf16* __restrict__ h,
                                              float* __restrict__ y) {
    __shared__ __align__(16) bf16 A[128][136];
    __shared__ __align__(16) bf16 B[128][72];
    __shared__ float dS[128], cS[128], b1S[128], b2S[128];
    __shared__ int a0S[128], a1S[128];
    int tid = threadIdx.x, e0 = blockIdx.x * 128;
    if (tid < 128) {
        int e = e0 + tid;
        dS[tid] = dArr[e]; cS[tid] = cArr[e];
        a0S[tid] = a[2 * e]; a1S[tid] = a[2 * e + 1];
        b1S[tid] = fb1_t[tid]; b2S[tid] = fb2_t[tid];
    }
    stage_b(&B[0][0], fw1T_t, 0, 128, 64, tid);
    __syncthreads();
    const float width = 5.0f / 49.0f;
    const float coeff = -0.5f / (width * width);
    for (int idx = tid; idx < 128 * 64; idx += 256) {
        int i = idx >> 6, k = idx & 63;
        float v = 0.f;
        if (k < GG) { float t = dS[i] - (float)k * width; v = __expf(coeff * t * t); }
        A[i][k] = f2b(v);
    }
    __syncthreads();
    int wave = tid >> 6, lane = tid & 63, q = lane >> 4, ln = lane & 15;
    floatx4 acc[2][8];
#pragma unroll
    for (int i = 0; i < 2; i++)
#pragma unroll
        for (int j = 0; j < 8; j++) acc[i][j] = (floatx4){0.f, 0.f, 0.f, 0.f};
    mfma_half<8>(&A[0][0], &B[0][0], acc, 0, wave, q, ln);
#pragma unroll
    for (int rt = 0; rt < 2; rt++)
#pragma unroll
        for (int ct = 0; ct < 8; ct++)
#pragma unroll
            for (int rg = 0; rg < 4; rg++) {
                int row = wave * 32 + rt * 16 + q * 4 + rg, col = ct * 16 + ln;
                A[row][col] = f2b(sspf(acc[rt][ct][rg] + b1S[col]));
            }
    __syncthreads();
    stage_b(&B[0][0], fw2T_t, 0, 128, 128, tid);
    __syncthreads();
#pragma unroll
    for (int i = 0; i < 2; i++)
#pragma unroll
        for (int j = 0; j < 8; j++) acc[i][j] = (floatx4){0.f, 0.f, 0.f, 0.f};
    mfma_half<8>(&A[0][0], &B[0][0], acc, 0, wave, q, ln);
    __syncthreads();
    stage_b(&B[0][0], fw2T_t, 64, 128, 128, tid);
    __syncthreads();
    mfma_half<8>(&A[0][0], &B[0][0], acc, 64, wave, q, ln);
#pragma unroll
    for (int rt = 0; rt < 2; rt++)
#pragma unroll
        for (int ct = 0; ct < 8; ct++)
#pragma unroll
            for (int rg = 0; rg < 4; rg++) {
                int row = wave * 32 + rt * 16 + q * 4 + rg, col = ct * 16 + ln;
                float w = (acc[rt][ct][rg] + b2S[col]) * cS[row];
                int A0 = a0S[row], A1 = a1S[row];
                float h0 = b2f(h[A0 * FF + col]);
                float h1 = b2f(h[A1 * FF + col]);
                atomicAdd(&y[A0 * FF + col], h1 * w);
                atomicAdd(&y[A1 * FF + col], h0 * w);
            }
}

__global__ __launch_bounds__(256) void k_node(const float* __restrict__ y,
                                              const bf16* __restrict__ wout1T_t,
                                              const float* __restrict__ bo1_t,
                                              const bf16* __restrict__ wout2T_t,
                                              const float* __restrict__ bo2_t,
                                              float* __restrict__ r) {
    __shared__ __align__(16) bf16 A[128][136];
    __shared__ __align__(16) bf16 B[128][72];
    __shared__ float b1S[128], b2S[128];
    int tid = threadIdx.x, n0 = blockIdx.x * 128;
    if (tid < 128) { b1S[tid] = bo1_t[tid]; b2S[tid] = bo2_t[tid]; }
    for (int idx = tid; idx < 128 * 128; idx += 256) {
        int row = idx >> 7, col = idx & 127;
        A[row][col] = f2b(y[(size_t)(n0 + row) * FF + col]);
    }
    stage_b(&B[0][0], wout1T_t, 0, 128, 128, tid);
    __syncthreads();
    int wave = tid >> 6, lane = tid & 63, q = lane >> 4, ln = lane & 15;
    floatx4 acc[2][8];
#pragma unroll
    for (int i = 0; i < 2; i++)
#pragma unroll
        for (int j = 0; j < 8; j++) acc[i][j] = (floatx4){0.f, 0.f, 0.f, 0.f};
    mfma_half<8>(&A[0][0], &B[0][0], acc, 0, wave, q, ln);
    __syncthreads();
    stage_b(&B[0][0], wout1T_t, 64, 128, 128, tid);
    __syncthreads();
    mfma_half<8>(&A[0][0], &B[0][0], acc, 64, wave, q, ln);
#pragma unroll
    for (int rt = 0; rt < 2; rt++)
#pragma unroll
        for (int ct = 0; ct < 8; ct++)
#pragma unroll
            for (int rg = 0; rg < 4; rg++) {
                int row = wave * 32 + rt * 16 + q * 4 + rg, col = ct * 16 + ln;
                A[row][col] = f2b(sspf(acc[rt][ct][rg] + b1S[col]));
            }
    __syncthreads();
    stage_b(&B[0][0], wout2T_t, 0, 128, 128, tid);
    __syncthreads();
#pragma unroll
    for (int i = 0; i < 2; i++)
#pragma unroll
        for (int j = 0; j < 8; j++) acc[i][j] = (floatx4){0.f, 0.f, 0.f, 0.f};
    mfma_half<8>(&A[0][0], &B[0][0], acc, 0, wave, q, ln);
    __syncthreads();
    stage_b(&B[0][0], wout2T_t, 64, 128, 128, tid);
    __syncthreads();
    mfma_half<8>(&A[0][0], &B[0][0], acc, 64, wave, q, ln);
#pragma unroll
    for (int rt = 0; rt < 2; rt++)
#pragma unroll
        for (int ct = 0; ct < 8; ct++)
#pragma unroll
            for (int rg = 0; rg < 4; rg++) {
                int row = wave * 32 + rt * 16 + q * 4 + rg, col = ct * 16 + ln;
                size_t off = (size_t)(n0 + row) * DD + col;
                r[off] += acc[rt][ct][rg] + b2S[col];
            }
}

// ---------------------------------------------------------------------------
__global__ __launch_bounds__(256) void k_head(const float* __restrict__ r,
                                              const bf16* __restrict__ wa1T,
                                              const float* __restrict__ ba1,
                                              const float* __restrict__ wa2,
                                              const float* __restrict__ ba2,
                                              const int* __restrict__ mol,
                                              float* __restrict__ molE) {
    __shared__ __align__(16) bf16 A[128][136];
    __shared__ __align__(16) bf16 B[64][72];
    __shared__ __align__(16) bf16 U[128][72];
    __shared__ float wa2S[64], ba1S[64];
    int tid = threadIdx.x, n0 = blockIdx.x * 128;
    if (tid < 64) { wa2S[tid] = wa2[tid]; ba1S[tid] = ba1[tid]; }
    for (int i = tid; i < 128 * 32; i += 256) {
        int row = i >> 5, c4 = (i & 31) * 4;
        float4 v = *(const float4*)(r + (size_t)(n0 + row) * DD + c4);
        A[row][c4]     = f2b(v.x);
        A[row][c4 + 1] = f2b(v.y);
        A[row][c4 + 2] = f2b(v.z);
        A[row][c4 + 3] = f2b(v.w);
    }
    stage_b(&B[0][0], wa1T, 0, 64, 128, tid);
    __syncthreads();
    int wave = tid >> 6, lane = tid & 63, q = lane >> 4, ln = lane & 15;
    floatx4 acc[2][4];
#pragma unroll
    for (int i = 0; i < 2; i++)
#pragma unroll
        for (int j = 0; j < 4; j++) acc[i][j] = (floatx4){0.f, 0.f, 0.f, 0.f};
    mfma_half<4>(&A[0][0], &B[0][0], acc, 0, wave, q, ln);
    __syncthreads();
    stage_b(&B[0][0], wa1T, 64, 64, 128, tid);
    __syncthreads();
    mfma_half<4>(&A[0][0], &B[0][0], acc, 64, wave, q, ln);
#pragma unroll
    for (int rt = 0; rt < 2; rt++)
#pragma unroll
        for (int ct = 0; ct < 4; ct++)
#pragma unroll
            for (int rg = 0; rg < 4; rg++) {
                int row = wave * 32 + rt * 16 + q * 4 + rg, col = ct * 16 + ln;
                U[row][col] = f2b(acc[rt][ct][rg] + ba1S[col]);
            }
    __syncthreads();
    if (tid < 128) {
        float s = ba2[0];
#pragma unroll
        for (int j = 0; j < 64; j++) s += sspf(b2f(U[tid][j])) * wa2S[j];
        atomicAdd(&molE[mol[n0 + tid]], s);
    }
}

__global__ __launch_bounds__(256) void k_out(const float* __restrict__ molE,
                                             float* __restrict__ out) {
    int i = blockIdx.x * 256 + threadIdx.x;
    out[i] = molE[i];
}

// ---------------------------------------------------------------------------
extern "C" void kernel_launch(void* const* d_in, const int* in_sizes, int n_in,
                              void* d_out, int out_size, void* d_ws, size_t ws_size,
                              hipStream_t stream) {
    const float* xyz   = (const float*)d_in[0];
    const float* emb   = (const float*)d_in[1];
    const float* fw1   = (const float*)d_in[2];
    const float* fb1   = (const float*)d_in[3];
    const float* fw2   = (const float*)d_in[4];
    const float* fb2   = (const float*)d_in[5];
    const float* win   = (const float*)d_in[6];
    const float* wout1 = (const float*)d_in[7];
    const float* bout1 = (const float*)d_in[8];
    const float* wout2 = (const float*)d_in[9];
    const float* bout2 = (const float*)d_in[10];
    const float* wa1   = (const float*)d_in[11];
    const float* ba1   = (const float*)d_in[12];
    const float* wa2   = (const float*)d_in[13];
    const float* ba2   = (const float*)d_in[14];
    const int*  z     = (const int*)d_in[15];
    const int*  a     = (const int*)d_in[16];
    const int*  mol   = (const int*)d_in[17];

    char* ws = (char*)d_ws;
    float* r    = (float*)ws; ws += (size_t)N_ATOMS * DD * 4;     //  67,108,864
    bf16*  h    = (bf16*) ws; ws += (size_t)N_ATOMS * FF * 2;     //  33,554,432
    float* dA   = (float*)ws; ws += (size_t)N_EDGES * 4;          //   2,097,152
    float* cA   = (float*)ws; ws += (size_t)N_EDGES * 4;          //   2,097,152
    float* molE = (float*)ws; ws += (size_t)N_MOLS * 4;           //       8,192
    bf16*  fw1T   = (bf16*)ws; ws += 3 * 128 * 64 * 2;
    bf16*  fw2T   = (bf16*)ws; ws += 3 * 128 * 128 * 2;
    bf16*  winT   = (bf16*)ws; ws += 3 * 128 * 128 * 2;
    bf16*  wout1T = (bf16*)ws; ws += 3 * 128 * 128 * 2;
    bf16*  wout2T = (bf16*)ws; ws += 3 * 128 * 128 * 2;
    bf16*  wa1T   = (bf16*)ws; ws += 64 * 128 * 2;
    char*  csr_base = ws;                                          // fallback y aliases here
    int*   ptr    = (int*)ws;  ws += 524320;                      // N_ATOMS+1 ints, padded
    int*   cursor = (int*)ws;  ws += (size_t)N_ATOMS * 4;
    int*   eslot  = (int*)ws;  ws += (size_t)2 * N_EDGES * 4;     //   4,194,304
    bf16*  Pcsr   = (bf16*)ws; ws += (size_t)2 * N_EDGES * FF * 2; // 268,435,456
    size_t need = (size_t)(ws - (char*)d_ws);                     // ~379 MB

    k_init<<<N_ATOMS * DD / 256, 256, 0, stream>>>(emb, z, r);
    k_dist<<<N_EDGES / 256, 256, 0, stream>>>(xyz, a, dA, cA, molE);
    k_wt<<<896, 256, 0, stream>>>(fw1, fw2, win, wout1, wout2, wa1,
                                  fw1T, fw2T, winT, wout1T, wout2T, wa1T);

    if (ws_size >= need) {
        // CSR build (edge list constant across t)
        k_zero<<<(N_ATOMS + 255) / 256, 256, 0, stream>>>(cursor, N_ATOMS);
        k_count<<<N_EDGES / 256, 256, 0, stream>>>(a, cursor);
        k_scan<<<1, 256, 0, stream>>>(cursor, ptr);
        k_fill<<<N_EDGES / 256, 256, 0, stream>>>(a, cursor, eslot);
        for (int t = 0; t < TT; t++) {
            k_h<<<N_ATOMS / 128, 256, 0, stream>>>(r, winT + t * 16384, h, nullptr);
            k_edge_w<<<N_EDGES / 128, 256, 0, stream>>>(dA, cA, a, eslot,
                                                        fw1T + t * 8192, fb1 + t * FF,
                                                        fw2T + t * 16384, fb2 + t * FF,
                                                        h, Pcsr);
            k_seg_node<<<N_ATOMS / 128, 256, 0, stream>>>(ptr, Pcsr,
                                                          wout1T + t * 16384, bout1 + t * DD,
                                                          wout2T + t * 16384, bout2 + t * DD, r);
        }
    } else {
        // fallback: round-2 verified atomic-scatter path (y aliases CSR region)
        float* y = (float*)csr_base;
        for (int t = 0; t < TT; t++) {
            k_h<<<N_ATOMS / 128, 256, 0, stream>>>(r, winT + t * 16384, h, y);
            k_edge<<<N_EDGES / 128, 256, 0, stream>>>(dA, cA, a,
                                                      fw1T + t * 8192, fb1 + t * FF,
                                                      fw2T + t * 16384, fb2 + t * FF, h, y);
            k_node<<<N_ATOMS / 128, 256, 0, stream>>>(y, wout1T + t * 16384, bout1 + t * DD,
                                                      wout2T + t * 16384, bout2 + t * DD, r);
        }
    }
    k_head<<<N_ATOMS / 128, 256, 0, stream>>>(r, wa1T, ba1, wa2, ba2, mol, molE);
    k_out<<<N_MOLS / 256, 256, 0, stream>>>(molE, (float*)d_out);
}

// Round 5
// 1581.443 us; speedup vs baseline: 1.4007x; 1.2721x over previous
//
#include <hip/hip_runtime.h>
#include <hip/hip_bf16.h>

#define N_ATOMS 131072
#define N_EDGES 524288
#define N_MOLS  2048
#define DD      128   // n_atom_basis
#define FF      128   // n_filters
#define GG      50    // n_gaussians
#define TT      3

typedef __hip_bfloat16 bf16;
typedef __attribute__((ext_vector_type(8))) short short8;
typedef __attribute__((ext_vector_type(4))) float floatx4;

__device__ __forceinline__ float b2f(bf16 v) { return __bfloat162float(v); }
__device__ __forceinline__ bf16  f2b(float v) { return __float2bfloat16(v); }

__device__ __forceinline__ unsigned short b2us(bf16 v) {
    union { bf16 b; unsigned short u; } c; c.b = v; return c.u;
}

// unpack two bf16 (packed in a uint, low half = lower address) to float2
__device__ __forceinline__ float2 up2(unsigned int u) {
    float2 f;
    f.x = __uint_as_float(u << 16);
    f.y = __uint_as_float(u & 0xffff0000u);
    return f;
}

// shifted softplus: softplus(x) - ln2, numerically stable
__device__ __forceinline__ float sspf(float x) {
    return fmaxf(x, 0.f) + log1pf(__expf(-fabsf(x))) - 0.69314718056f;
}

// ---------------------------------------------------------------------------
// MFMA helpers.
// 128-row variant (fallback path): A[128][136], wave owns rows [32w,32w+32).
// 64-row variant (main path): A[64][136], wave owns rows [16w,16w+16).
// B tile: [n][72] bf16 LDS holding B^T chunk: B[n][kk], kk<64.
// 16x16x32 bf16 layouts: A[m=lane&15][k=q*8+j], B[k=q*8+j][n=lane&15],
// D[row=q*4+reg][col=lane&15].  (verified, learn_hip m89)
// ---------------------------------------------------------------------------
template <int NCT>
__device__ __forceinline__ void mfma_half(const bf16* A, const bf16* B,
                                          floatx4 (&acc)[2][NCT],
                                          int kA, int wave, int q, int ln) {
#pragma unroll
    for (int k0 = 0; k0 < 64; k0 += 32) {
        short8 a0 = *(const short8*)(A + (wave * 32 + ln) * 136 + kA + k0 + q * 8);
        short8 a1 = *(const short8*)(A + (wave * 32 + 16 + ln) * 136 + kA + k0 + q * 8);
#pragma unroll
        for (int ct = 0; ct < NCT; ct++) {
            short8 b = *(const short8*)(B + (ct * 16 + ln) * 72 + k0 + q * 8);
            acc[0][ct] = __builtin_amdgcn_mfma_f32_16x16x32_bf16(a0, b, acc[0][ct], 0, 0, 0);
            acc[1][ct] = __builtin_amdgcn_mfma_f32_16x16x32_bf16(a1, b, acc[1][ct], 0, 0, 0);
        }
    }
}

template <int NCT>
__device__ __forceinline__ void mfma64(const bf16* A, const bf16* B,
                                       floatx4 (&acc)[NCT],
                                       int kA, int wave, int q, int ln) {
#pragma unroll
    for (int k0 = 0; k0 < 64; k0 += 32) {
        short8 a = *(const short8*)(A + (wave * 16 + ln) * 136 + kA + k0 + q * 8);
#pragma unroll
        for (int ct = 0; ct < NCT; ct++) {
            short8 b = *(const short8*)(B + (ct * 16 + ln) * 72 + k0 + q * 8);
            acc[ct] = __builtin_amdgcn_mfma_f32_16x16x32_bf16(a, b, acc[ct], 0, 0, 0);
        }
    }
}

__device__ __forceinline__ void stage_b(bf16* B, const bf16* WT, int k0,
                                        int nrows, int ldk, int tid) {
    for (int i = tid; i < nrows * 8; i += 256) {
        int n = i >> 3, kc = i & 7;
        *(short8*)(B + n * 72 + kc * 8) =
            *(const short8*)(WT + n * ldk + k0 + kc * 8);
    }
}

// ---------------------------------------------------------------------------
__global__ __launch_bounds__(256) void k_init(const float* __restrict__ emb,
                                              const int* __restrict__ z,
                                              float* __restrict__ r) {
    int idx = blockIdx.x * 256 + threadIdx.x;
    int atom = idx >> 7, col = idx & 127;
    r[idx] = emb[z[atom] * DD + col];
}

__global__ __launch_bounds__(256) void k_dist(const float* __restrict__ xyz,
                                              const int* __restrict__ a,
                                              float* __restrict__ dArr,
                                              float* __restrict__ cArr,
                                              float* __restrict__ molE) {
    int e = blockIdx.x * 256 + threadIdx.x;
    if (e < N_MOLS) molE[e] = 0.f;
    int A0 = a[2 * e], A1 = a[2 * e + 1];
    float dx = xyz[3 * A0]     - xyz[3 * A1];
    float dy = xyz[3 * A0 + 1] - xyz[3 * A1 + 1];
    float dz = xyz[3 * A0 + 2] - xyz[3 * A1 + 2];
    float d = sqrtf(dx * dx + dy * dy + dz * dz);
    dArr[e] = d;
    cArr[e] = 0.5f * (__cosf(d * 0.6283185307179586f) + 1.f);
}

__global__ __launch_bounds__(256) void k_wt(const float* __restrict__ fw1,
                                            const float* __restrict__ fw2,
                                            const float* __restrict__ win,
                                            const float* __restrict__ wout1,
                                            const float* __restrict__ wout2,
                                            const float* __restrict__ wa1,
                                            bf16* __restrict__ fw1T, bf16* __restrict__ fw2T,
                                            bf16* __restrict__ winT, bf16* __restrict__ wout1T,
                                            bf16* __restrict__ wout2T, bf16* __restrict__ wa1T) {
    int idx = blockIdx.x * 256 + threadIdx.x;
    if (idx < 3 * 128 * 64) {
        int t = idx / 8192, j = idx % 8192;
        int n = j >> 6, k = j & 63;
        fw1T[idx] = (k < GG) ? f2b(fw1[t * GG * FF + k * FF + n]) : f2b(0.f);
        return;
    }
    idx -= 3 * 128 * 64;
    if (idx < 3 * 16384) { int t = idx / 16384, j = idx % 16384; int n = j >> 7, k = j & 127;
        fw2T[idx] = f2b(fw2[t * 16384 + k * 128 + n]); return; }
    idx -= 3 * 16384;
    if (idx < 3 * 16384) { int t = idx / 16384, j = idx % 16384; int n = j >> 7, k = j & 127;
        winT[idx] = f2b(win[t * 16384 + k * 128 + n]); return; }
    idx -= 3 * 16384;
    if (idx < 3 * 16384) { int t = idx / 16384, j = idx % 16384; int n = j >> 7, k = j & 127;
        wout1T[idx] = f2b(wout1[t * 16384 + k * 128 + n]); return; }
    idx -= 3 * 16384;
    if (idx < 3 * 16384) { int t = idx / 16384, j = idx % 16384; int n = j >> 7, k = j & 127;
        wout2T[idx] = f2b(wout2[t * 16384 + k * 128 + n]); return; }
    idx -= 3 * 16384;
    if (idx < 64 * 128) { int n = idx >> 7, k = idx & 127;
        wa1T[idx] = f2b(wa1[k * 64 + n]); return; }
}

// ---------------------------------------------------------------------------
// CSR build (once per launch; edge list is constant across t)
__global__ __launch_bounds__(256) void k_zero(int* __restrict__ p, int n) {
    int i = blockIdx.x * 256 + threadIdx.x;
    if (i < n) p[i] = 0;
}

__global__ __launch_bounds__(256) void k_count(const int* __restrict__ a,
                                               int* __restrict__ counts) {
    int e = blockIdx.x * 256 + threadIdx.x;
    atomicAdd(&counts[a[2 * e]], 1);
    atomicAdd(&counts[a[2 * e + 1]], 1);
}

// single block: exclusive prefix sum of counts[N_ATOMS] -> ptr; cursor = ptr copy
__global__ __launch_bounds__(256) void k_scan(int* __restrict__ counts,
                                              int* __restrict__ ptr) {
    __shared__ int part[256];
    int tid = threadIdx.x;
    const int CH = N_ATOMS / 256;  // 512
    int base = tid * CH;
    int s = 0;
    for (int i = 0; i < CH; i++) s += counts[base + i];
    part[tid] = s;
    __syncthreads();
    if (tid == 0) {
        int acc = 0;
        for (int i = 0; i < 256; i++) { int v = part[i]; part[i] = acc; acc += v; }
    }
    __syncthreads();
    int run = part[tid];
    for (int i = 0; i < CH; i++) {
        int v = counts[base + i];
        ptr[base + i] = run;
        counts[base + i] = run;   // counts buffer becomes the fill cursor
        run += v;
    }
    if (tid == 255) ptr[N_ATOMS] = run;  // == 2E
}

// adj[slot] = (edge id, other atom)  -- slots contiguous per atom
__global__ __launch_bounds__(256) void k_fill(const int* __restrict__ a,
                                              int* __restrict__ cursor,
                                              int* __restrict__ adj) {
    int e = blockIdx.x * 256 + threadIdx.x;
    int A0 = a[2 * e], A1 = a[2 * e + 1];
    int p0 = atomicAdd(&cursor[A0], 1);
    adj[2 * p0] = e; adj[2 * p0 + 1] = A1;
    int p1 = atomicAdd(&cursor[A1], 1);
    adj[2 * p1] = e; adj[2 * p1 + 1] = A0;
}

// ---------------------------------------------------------------------------
// MAIN PATH: 64-row tiles, ~37 KB LDS -> 4 blocks/CU (16 waves)
// ---------------------------------------------------------------------------

// h = bf16(r) @ win[t]
__global__ __launch_bounds__(256, 4) void k_h64(const float* __restrict__ r,
                                                const bf16* __restrict__ winT_t,
                                                bf16* __restrict__ h) {
    __shared__ __align__(16) bf16 A[64][136];
    __shared__ __align__(16) bf16 B[128][72];
    int tid = threadIdx.x, n0 = blockIdx.x * 64;
    for (int i = tid; i < 64 * 32; i += 256) {
        int row = i >> 5, c4 = (i & 31) * 4;
        float4 v = *(const float4*)(r + (size_t)(n0 + row) * DD + c4);
        A[row][c4]     = f2b(v.x);
        A[row][c4 + 1] = f2b(v.y);
        A[row][c4 + 2] = f2b(v.z);
        A[row][c4 + 3] = f2b(v.w);
    }
    stage_b(&B[0][0], winT_t, 0, 128, 128, tid);
    __syncthreads();
    int wave = tid >> 6, lane = tid & 63, q = lane >> 4, ln = lane & 15;
    floatx4 acc[8];
#pragma unroll
    for (int j = 0; j < 8; j++) acc[j] = (floatx4){0.f, 0.f, 0.f, 0.f};
    mfma64<8>(&A[0][0], &B[0][0], acc, 0, wave, q, ln);
    __syncthreads();
    stage_b(&B[0][0], winT_t, 64, 128, 128, tid);
    __syncthreads();
    mfma64<8>(&A[0][0], &B[0][0], acc, 64, wave, q, ln);
#pragma unroll
    for (int ct = 0; ct < 8; ct++)
#pragma unroll
        for (int rg = 0; rg < 4; rg++) {
            int row = wave * 16 + q * 4 + rg, col = ct * 16 + ln;
            h[(size_t)(n0 + row) * FF + col] = f2b(acc[ct][rg]);
        }
}

// edge filter: Wt[e][:] = bf16( (ssp(g@fw1+b1)@fw2 + b2) * C )
__global__ __launch_bounds__(256, 4) void k_edge_w64(const float* __restrict__ dArr,
                                                     const float* __restrict__ cArr,
                                                     const bf16* __restrict__ fw1T_t,
                                                     const float* __restrict__ fb1_t,
                                                     const bf16* __restrict__ fw2T_t,
                                                     const float* __restrict__ fb2_t,
                                                     bf16* __restrict__ Wt) {
    __shared__ __align__(16) bf16 A[64][136];
    __shared__ __align__(16) bf16 B[128][72];
    __shared__ float dS[64], cS[64], b1S[128], b2S[128];
    int tid = threadIdx.x, e0 = blockIdx.x * 64;
    if (tid < 64) { dS[tid] = dArr[e0 + tid]; cS[tid] = cArr[e0 + tid]; }
    if (tid < 128) { b1S[tid] = fb1_t[tid]; b2S[tid] = fb2_t[tid]; }
    stage_b(&B[0][0], fw1T_t, 0, 128, 64, tid);
    __syncthreads();   // dS visible before g-smear
    const float width = 5.0f / 49.0f;
    const float coeff = -0.5f / (width * width);
    for (int idx = tid; idx < 64 * 64; idx += 256) {
        int i = idx >> 6, k = idx & 63;
        float v = 0.f;
        if (k < GG) { float t = dS[i] - (float)k * width; v = __expf(coeff * t * t); }
        A[i][k] = f2b(v);
    }
    __syncthreads();
    int wave = tid >> 6, lane = tid & 63, q = lane >> 4, ln = lane & 15;
    floatx4 acc[8];
#pragma unroll
    for (int j = 0; j < 8; j++) acc[j] = (floatx4){0.f, 0.f, 0.f, 0.f};
    mfma64<8>(&A[0][0], &B[0][0], acc, 0, wave, q, ln);   // K=64 (padded from 50)
    // u = ssp(.+b1) -> A own rows (other waves never read our rows)
#pragma unroll
    for (int ct = 0; ct < 8; ct++)
#pragma unroll
        for (int rg = 0; rg < 4; rg++) {
            int row = wave * 16 + q * 4 + rg, col = ct * 16 + ln;
            A[row][col] = f2b(sspf(acc[ct][rg] + b1S[col]));
        }
    __syncthreads();
    stage_b(&B[0][0], fw2T_t, 0, 128, 128, tid);
    __syncthreads();
#pragma unroll
    for (int j = 0; j < 8; j++) acc[j] = (floatx4){0.f, 0.f, 0.f, 0.f};
    mfma64<8>(&A[0][0], &B[0][0], acc, 0, wave, q, ln);
    __syncthreads();
    stage_b(&B[0][0], fw2T_t, 64, 128, 128, tid);
    __syncthreads();
    mfma64<8>(&A[0][0], &B[0][0], acc, 64, wave, q, ln);
#pragma unroll
    for (int ct = 0; ct < 8; ct++)
#pragma unroll
        for (int rg = 0; rg < 4; rg++) {
            int row = wave * 16 + q * 4 + rg, col = ct * 16 + ln;
            A[row][col] = f2b((acc[ct][rg] + b2S[col]) * cS[row]);
        }
    __syncthreads();
    for (int i = tid; i < 64 * 16; i += 256) {
        int row = i >> 4, seg = i & 15;
        *(uint4*)(Wt + (size_t)(e0 + row) * FF + seg * 8) =
            *(const uint4*)(&A[row][seg * 8]);
    }
}

// cooperative gather (16B/lane, 4 slots in flight) + fused node MLP; r += dr
__global__ __launch_bounds__(256, 4) void k_gather_node64(const int* __restrict__ ptr,
                                                          const int* __restrict__ adj,
                                                          const bf16* __restrict__ Wt,
                                                          const bf16* __restrict__ h,
                                                          const bf16* __restrict__ wout1T_t,
                                                          const float* __restrict__ bo1_t,
                                                          const bf16* __restrict__ wout2T_t,
                                                          const float* __restrict__ bo2_t,
                                                          float* __restrict__ r) {
    __shared__ __align__(16) bf16 A[64][136];
    __shared__ __align__(16) bf16 B[128][72];
    __shared__ float b1S[128], b2S[128];
    int tid = threadIdx.x, n0 = blockIdx.x * 64;
    if (tid < 128) { b1S[tid] = bo1_t[tid]; b2S[tid] = bo2_t[tid]; }
    int wave = tid >> 6, lane = tid & 63;
    int seg = lane & 15;   // column segment: cols [8*seg, 8*seg+8)
    int rg  = lane >> 4;   // slot-in-group 0..3
    for (int k = 0; k < 16; k++) {
        int row = wave * 16 + k;
        int atom = n0 + row;
        int beg = ptr[atom], end = ptr[atom + 1];
        float ac[8];
#pragma unroll
        for (int j = 0; j < 8; j++) ac[j] = 0.f;
        for (int s0 = beg; s0 < end; s0 += 4) {
            int slot = s0 + rg;
            if (slot < end) {
                int2 eo = *(const int2*)(adj + 2 * slot);
                uint4 wv = *(const uint4*)(Wt + (size_t)eo.x * FF + seg * 8);
                uint4 hv = *(const uint4*)(h + (size_t)eo.y * FF + seg * 8);
                float2 w0 = up2(wv.x), h0 = up2(hv.x);
                float2 w1 = up2(wv.y), h1 = up2(hv.y);
                float2 w2 = up2(wv.z), h2 = up2(hv.z);
                float2 w3 = up2(wv.w), h3 = up2(hv.w);
                ac[0] = fmaf(w0.x, h0.x, ac[0]); ac[1] = fmaf(w0.y, h0.y, ac[1]);
                ac[2] = fmaf(w1.x, h1.x, ac[2]); ac[3] = fmaf(w1.y, h1.y, ac[3]);
                ac[4] = fmaf(w2.x, h2.x, ac[4]); ac[5] = fmaf(w2.y, h2.y, ac[5]);
                ac[6] = fmaf(w3.x, h3.x, ac[6]); ac[7] = fmaf(w3.y, h3.y, ac[7]);
            }
        }
        // reduce over the 4 slot-groups (lanes rg=0..3 at stride 16)
#pragma unroll
        for (int j = 0; j < 8; j++) {
            float v = ac[j];
            v += __shfl_down(v, 32);
            v += __shfl_down(v, 16);
            ac[j] = v;
        }
        if (rg == 0) {
            uint4 o;
            o.x = ((unsigned)b2us(f2b(ac[1])) << 16) | b2us(f2b(ac[0]));
            o.y = ((unsigned)b2us(f2b(ac[3])) << 16) | b2us(f2b(ac[2]));
            o.z = ((unsigned)b2us(f2b(ac[5])) << 16) | b2us(f2b(ac[4]));
            o.w = ((unsigned)b2us(f2b(ac[7])) << 16) | b2us(f2b(ac[6]));
            *(uint4*)(&A[row][seg * 8]) = o;
        }
    }
    stage_b(&B[0][0], wout1T_t, 0, 128, 128, tid);
    __syncthreads();
    int q = lane >> 4, ln = lane & 15;
    floatx4 acc[8];
#pragma unroll
    for (int j = 0; j < 8; j++) acc[j] = (floatx4){0.f, 0.f, 0.f, 0.f};
    mfma64<8>(&A[0][0], &B[0][0], acc, 0, wave, q, ln);
    __syncthreads();
    stage_b(&B[0][0], wout1T_t, 64, 128, 128, tid);
    __syncthreads();
    mfma64<8>(&A[0][0], &B[0][0], acc, 64, wave, q, ln);
#pragma unroll
    for (int ct = 0; ct < 8; ct++)
#pragma unroll
        for (int rgi = 0; rgi < 4; rgi++) {
            int row = wave * 16 + q * 4 + rgi, col = ct * 16 + ln;
            A[row][col] = f2b(sspf(acc[ct][rgi] + b1S[col]));
        }
    __syncthreads();
    stage_b(&B[0][0], wout2T_t, 0, 128, 128, tid);
    __syncthreads();
#pragma unroll
    for (int j = 0; j < 8; j++) acc[j] = (floatx4){0.f, 0.f, 0.f, 0.f};
    mfma64<8>(&A[0][0], &B[0][0], acc, 0, wave, q, ln);
    __syncthreads();
    stage_b(&B[0][0], wout2T_t, 64, 128, 128, tid);
    __syncthreads();
    mfma64<8>(&A[0][0], &B[0][0], acc, 64, wave, q, ln);
#pragma unroll
    for (int ct = 0; ct < 8; ct++)
#pragma unroll
        for (int rgi = 0; rgi < 4; rgi++) {
            int row = wave * 16 + q * 4 + rgi, col = ct * 16 + ln;
            size_t off = (size_t)(n0 + row) * DD + col;
            r[off] += acc[ct][rgi] + b2S[col];
        }
}

// ---------------------------------------------------------------------------
// FALLBACK (round-2 verified): fused atomic scatter + separate k_h/k_node
// ---------------------------------------------------------------------------
__global__ __launch_bounds__(256) void k_h(const float* __restrict__ r,
                                           const bf16* __restrict__ winT_t,
                                           bf16* __restrict__ h,
                                           float* __restrict__ y) {
    __shared__ __align__(16) bf16 A[128][136];
    __shared__ __align__(16) bf16 B[128][72];
    int tid = threadIdx.x, n0 = blockIdx.x * 128;
    for (int i = tid; i < 128 * 32; i += 256) {
        int row = i >> 5, c4 = (i & 31) * 4;
        float4 v = *(const float4*)(r + (size_t)(n0 + row) * DD + c4);
        A[row][c4]     = f2b(v.x);
        A[row][c4 + 1] = f2b(v.y);
        A[row][c4 + 2] = f2b(v.z);
        A[row][c4 + 3] = f2b(v.w);
        *(float4*)(y + (size_t)(n0 + row) * FF + c4) = (float4){0.f, 0.f, 0.f, 0.f};
    }
    stage_b(&B[0][0], winT_t, 0, 128, 128, tid);
    __syncthreads();
    int wave = tid >> 6, lane = tid & 63, q = lane >> 4, ln = lane & 15;
    floatx4 acc[2][8];
#pragma unroll
    for (int i = 0; i < 2; i++)
#pragma unroll
        for (int j = 0; j < 8; j++) acc[i][j] = (floatx4){0.f, 0.f, 0.f, 0.f};
    mfma_half<8>(&A[0][0], &B[0][0], acc, 0, wave, q, ln);
    __syncthreads();
    stage_b(&B[0][0], winT_t, 64, 128, 128, tid);
    __syncthreads();
    mfma_half<8>(&A[0][0], &B[0][0], acc, 64, wave, q, ln);
#pragma unroll
    for (int rt = 0; rt < 2; rt++)
#pragma unroll
        for (int ct = 0; ct < 8; ct++)
#pragma unroll
            for (int rg = 0; rg < 4; rg++) {
                int row = wave * 32 + rt * 16 + q * 4 + rg, col = ct * 16 + ln;
                h[(size_t)(n0 + row) * FF + col] = f2b(acc[rt][ct][rg]);
            }
}

__global__ __launch_bounds__(256) void k_edge(const float* __restrict__ dArr,
                                              const float* __restrict__ cArr,
                                              const int* __restrict__ a,
                                              const bf16* __restrict__ fw1T_t,
                                              const float* __restrict__ fb1_t,
                                              const bf16* __restrict__ fw2T_t,
                                              const float* __restrict__ fb2_t,
                                              const bf16* __restrict__ h,
                                              float* __restrict__ y) {
    __shared__ __align__(16) bf16 A[128][136];
    __shared__ __align__(16) bf16 B[128][72];
    __shared__ float dS[128], cS[128], b1S[128], b2S[128];
    __shared__ int a0S[128], a1S[128];
    int tid = threadIdx.x, e0 = blockIdx.x * 128;
    if (tid < 128) {
        int e = e0 + tid;
        dS[tid] = dArr[e]; cS[tid] = cArr[e];
        a0S[tid] = a[2 * e]; a1S[tid] = a[2 * e + 1];
        b1S[tid] = fb1_t[tid]; b2S[tid] = fb2_t[tid];
    }
    stage_b(&B[0][0], fw1T_t, 0, 128, 64, tid);
    __syncthreads();
    const float width = 5.0f / 49.0f;
    const float coeff = -0.5f / (width * width);
    for (int idx = tid; idx < 128 * 64; idx += 256) {
        int i = idx >> 6, k = idx & 63;
        float v = 0.f;
        if (k < GG) { float t = dS[i] - (float)k * width; v = __expf(coeff * t * t); }
        A[i][k] = f2b(v);
    }
    __syncthreads();
    int wave = tid >> 6, lane = tid & 63, q = lane >> 4, ln = lane & 15;
    floatx4 acc[2][8];
#pragma unroll
    for (int i = 0; i < 2; i++)
#pragma unroll
        for (int j = 0; j < 8; j++) acc[i][j] = (floatx4){0.f, 0.f, 0.f, 0.f};
    mfma_half<8>(&A[0][0], &B[0][0], acc, 0, wave, q, ln);
#pragma unroll
    for (int rt = 0; rt < 2; rt++)
#pragma unroll
        for (int ct = 0; ct < 8; ct++)
#pragma unroll
            for (int rg = 0; rg < 4; rg++) {
                int row = wave * 32 + rt * 16 + q * 4 + rg, col = ct * 16 + ln;
                A[row][col] = f2b(sspf(acc[rt][ct][rg] + b1S[col]));
            }
    __syncthreads();
    stage_b(&B[0][0], fw2T_t, 0, 128, 128, tid);
    __syncthreads();
#pragma unroll
    for (int i = 0; i < 2; i++)
#pragma unroll
        for (int j = 0; j < 8; j++) acc[i][j] = (floatx4){0.f, 0.f, 0.f, 0.f};
    mfma_half<8>(&A[0][0], &B[0][0], acc, 0, wave, q, ln);
    __syncthreads();
    stage_b(&B[0][0], fw2T_t, 64, 128, 128, tid);
    __syncthreads();
    mfma_half<8>(&A[0][0], &B[0][0], acc, 64, wave, q, ln);
#pragma unroll
    for (int rt = 0; rt < 2; rt++)
#pragma unroll
        for (int ct = 0; ct < 8; ct++)
#pragma unroll
            for (int rg = 0; rg < 4; rg++) {
                int row = wave * 32 + rt * 16 + q * 4 + rg, col = ct * 16 + ln;
                float w = (acc[rt][ct][rg] + b2S[col]) * cS[row];
                int A0 = a0S[row], A1 = a1S[row];
                float h0 = b2f(h[A0 * FF + col]);
                float h1 = b2f(h[A1 * FF + col]);
                atomicAdd(&y[A0 * FF + col], h1 * w);
                atomicAdd(&y[A1 * FF + col], h0 * w);
            }
}

__global__ __launch_bounds__(256) void k_node(const float* __restrict__ y,
                                              const bf16* __restrict__ wout1T_t,
                                              const float* __restrict__ bo1_t,
                                              const bf16* __restrict__ wout2T_t,
                                              const float* __restrict__ bo2_t,
                                              float* __restrict__ r) {
    __shared__ __align__(16) bf16 A[128][136];
    __shared__ __align__(16) bf16 B[128][72];
    __shared__ float b1S[128], b2S[128];
    int tid = threadIdx.x, n0 = blockIdx.x * 128;
    if (tid < 128) { b1S[tid] = bo1_t[tid]; b2S[tid] = bo2_t[tid]; }
    for (int idx = tid; idx < 128 * 128; idx += 256) {
        int row = idx >> 7, col = idx & 127;
        A[row][col] = f2b(y[(size_t)(n0 + row) * FF + col]);
    }
    stage_b(&B[0][0], wout1T_t, 0, 128, 128, tid);
    __syncthreads();
    int wave = tid >> 6, lane = tid & 63, q = lane >> 4, ln = lane & 15;
    floatx4 acc[2][8];
#pragma unroll
    for (int i = 0; i < 2; i++)
#pragma unroll
        for (int j = 0; j < 8; j++) acc[i][j] = (floatx4){0.f, 0.f, 0.f, 0.f};
    mfma_half<8>(&A[0][0], &B[0][0], acc, 0, wave, q, ln);
    __syncthreads();
    stage_b(&B[0][0], wout1T_t, 64, 128, 128, tid);
    __syncthreads();
    mfma_half<8>(&A[0][0], &B[0][0], acc, 64, wave, q, ln);
#pragma unroll
    for (int rt = 0; rt < 2; rt++)
#pragma unroll
        for (int ct = 0; ct < 8; ct++)
#pragma unroll
            for (int rg = 0; rg < 4; rg++) {
                int row = wave * 32 + rt * 16 + q * 4 + rg, col = ct * 16 + ln;
                A[row][col] = f2b(sspf(acc[rt][ct][rg] + b1S[col]));
            }
    __syncthreads();
    stage_b(&B[0][0], wout2T_t, 0, 128, 128, tid);
    __syncthreads();
#pragma unroll
    for (int i = 0; i < 2; i++)
#pragma unroll
        for (int j = 0; j < 8; j++) acc[i][j] = (floatx4){0.f, 0.f, 0.f, 0.f};
    mfma_half<8>(&A[0][0], &B[0][0], acc, 0, wave, q, ln);
    __syncthreads();
    stage_b(&B[0][0], wout2T_t, 64, 128, 128, tid);
    __syncthreads();
    mfma_half<8>(&A[0][0], &B[0][0], acc, 64, wave, q, ln);
#pragma unroll
    for (int rt = 0; rt < 2; rt++)
#pragma unroll
        for (int ct = 0; ct < 8; ct++)
#pragma unroll
            for (int rg = 0; rg < 4; rg++) {
                int row = wave * 32 + rt * 16 + q * 4 + rg, col = ct * 16 + ln;
                size_t off = (size_t)(n0 + row) * DD + col;
                r[off] += acc[rt][ct][rg] + b2S[col];
            }
}

// ---------------------------------------------------------------------------
__global__ __launch_bounds__(256) void k_head(const float* __restrict__ r,
                                              const bf16* __restrict__ wa1T,
                                              const float* __restrict__ ba1,
                                              const float* __restrict__ wa2,
                                              const float* __restrict__ ba2,
                                              const int* __restrict__ mol,
                                              float* __restrict__ molE) {
    __shared__ __align__(16) bf16 A[128][136];
    __shared__ __align__(16) bf16 B[64][72];
    __shared__ __align__(16) bf16 U[128][72];
    __shared__ float wa2S[64], ba1S[64];
    int tid = threadIdx.x, n0 = blockIdx.x * 128;
    if (tid < 64) { wa2S[tid] = wa2[tid]; ba1S[tid] = ba1[tid]; }
    for (int i = tid; i < 128 * 32; i += 256) {
        int row = i >> 5, c4 = (i & 31) * 4;
        float4 v = *(const float4*)(r + (size_t)(n0 + row) * DD + c4);
        A[row][c4]     = f2b(v.x);
        A[row][c4 + 1] = f2b(v.y);
        A[row][c4 + 2] = f2b(v.z);
        A[row][c4 + 3] = f2b(v.w);
    }
    stage_b(&B[0][0], wa1T, 0, 64, 128, tid);
    __syncthreads();
    int wave = tid >> 6, lane = tid & 63, q = lane >> 4, ln = lane & 15;
    floatx4 acc[2][4];
#pragma unroll
    for (int i = 0; i < 2; i++)
#pragma unroll
        for (int j = 0; j < 4; j++) acc[i][j] = (floatx4){0.f, 0.f, 0.f, 0.f};
    mfma_half<4>(&A[0][0], &B[0][0], acc, 0, wave, q, ln);
    __syncthreads();
    stage_b(&B[0][0], wa1T, 64, 64, 128, tid);
    __syncthreads();
    mfma_half<4>(&A[0][0], &B[0][0], acc, 64, wave, q, ln);
#pragma unroll
    for (int rt = 0; rt < 2; rt++)
#pragma unroll
        for (int ct = 0; ct < 4; ct++)
#pragma unroll
            for (int rg = 0; rg < 4; rg++) {
                int row = wave * 32 + rt * 16 + q * 4 + rg, col = ct * 16 + ln;
                U[row][col] = f2b(acc[rt][ct][rg] + ba1S[col]);
            }
    __syncthreads();
    if (tid < 128) {
        float s = ba2[0];
#pragma unroll
        for (int j = 0; j < 64; j++) s += sspf(b2f(U[tid][j])) * wa2S[j];
        atomicAdd(&molE[mol[n0 + tid]], s);
    }
}

__global__ __launch_bounds__(256) void k_out(const float* __restrict__ molE,
                                             float* __restrict__ out) {
    int i = blockIdx.x * 256 + threadIdx.x;
    out[i] = molE[i];
}

// ---------------------------------------------------------------------------
extern "C" void kernel_launch(void* const* d_in, const int* in_sizes, int n_in,
                              void* d_out, int out_size, void* d_ws, size_t ws_size,
                              hipStream_t stream) {
    const float* xyz   = (const float*)d_in[0];
    const float* emb   = (const float*)d_in[1];
    const float* fw1   = (const float*)d_in[2];
    const float* fb1   = (const float*)d_in[3];
    const float* fw2   = (const float*)d_in[4];
    const float* fb2   = (const float*)d_in[5];
    const float* win   = (const float*)d_in[6];
    const float* wout1 = (const float*)d_in[7];
    const float* bout1 = (const float*)d_in[8];
    const float* wout2 = (const float*)d_in[9];
    const float* bout2 = (const float*)d_in[10];
    const float* wa1   = (const float*)d_in[11];
    const float* ba1   = (const float*)d_in[12];
    const float* wa2   = (const float*)d_in[13];
    const float* ba2   = (const float*)d_in[14];
    const int*  z     = (const int*)d_in[15];
    const int*  a     = (const int*)d_in[16];
    const int*  mol   = (const int*)d_in[17];

    // layout identical to round-3 (need == 248,979,472 — proven to fit)
    char* ws = (char*)d_ws;
    float* r    = (float*)ws; ws += (size_t)N_ATOMS * DD * 4;     //  67,108,864
    bf16*  h    = (bf16*) ws; ws += (size_t)N_ATOMS * FF * 2;     //  33,554,432
    float* dA   = (float*)ws; ws += (size_t)N_EDGES * 4;          //   2,097,152
    float* cA   = (float*)ws; ws += (size_t)N_EDGES * 4;          //   2,097,152
    float* molE = (float*)ws; ws += (size_t)N_MOLS * 4;           //       8,192
    bf16*  fw1T   = (bf16*)ws; ws += 3 * 128 * 64 * 2;
    bf16*  fw2T   = (bf16*)ws; ws += 3 * 128 * 128 * 2;
    bf16*  winT   = (bf16*)ws; ws += 3 * 128 * 128 * 2;
    bf16*  wout1T = (bf16*)ws; ws += 3 * 128 * 128 * 2;
    bf16*  wout2T = (bf16*)ws; ws += 3 * 128 * 128 * 2;
    bf16*  wa1T   = (bf16*)ws; ws += 64 * 128 * 2;
    char*  csr_base = ws;                                          // fallback y aliases here
    int*   ptr    = (int*)ws;  ws += 524304;                      // N_ATOMS+1 ints, padded
    int*   cursor = (int*)ws;  ws += (size_t)N_ATOMS * 4;
    int*   adj    = (int*)ws;  ws += (size_t)2 * N_EDGES * 2 * 4; //   8,388,608
    bf16*  Wt     = (bf16*)ws; ws += (size_t)N_EDGES * FF * 2;    // 134,217,728
    size_t need = (size_t)(ws - (char*)d_ws);                     // 248,979,472

    k_init<<<N_ATOMS * DD / 256, 256, 0, stream>>>(emb, z, r);
    k_dist<<<N_EDGES / 256, 256, 0, stream>>>(xyz, a, dA, cA, molE);
    k_wt<<<896, 256, 0, stream>>>(fw1, fw2, win, wout1, wout2, wa1,
                                  fw1T, fw2T, winT, wout1T, wout2T, wa1T);

    if (ws_size >= need) {
        k_zero<<<(N_ATOMS + 255) / 256, 256, 0, stream>>>(cursor, N_ATOMS);
        k_count<<<N_EDGES / 256, 256, 0, stream>>>(a, cursor);
        k_scan<<<1, 256, 0, stream>>>(cursor, ptr);
        k_fill<<<N_EDGES / 256, 256, 0, stream>>>(a, cursor, adj);
        for (int t = 0; t < TT; t++) {
            k_h64<<<N_ATOMS / 64, 256, 0, stream>>>(r, winT + t * 16384, h);
            k_edge_w64<<<N_EDGES / 64, 256, 0, stream>>>(dA, cA,
                                                         fw1T + t * 8192, fb1 + t * FF,
                                                         fw2T + t * 16384, fb2 + t * FF, Wt);
            k_gather_node64<<<N_ATOMS / 64, 256, 0, stream>>>(ptr, adj, Wt, h,
                                                              wout1T + t * 16384, bout1 + t * DD,
                                                              wout2T + t * 16384, bout2 + t * DD, r);
        }
    } else {
        // fallback: round-2 verified atomic-scatter path (y aliases CSR region)
        float* y = (float*)csr_base;
        for (int t = 0; t < TT; t++) {
            k_h<<<N_ATOMS / 128, 256, 0, stream>>>(r, winT + t * 16384, h, y);
            k_edge<<<N_EDGES / 128, 256, 0, stream>>>(dA, cA, a,
                                                      fw1T + t * 8192, fb1 + t * FF,
                                                      fw2T + t * 16384, fb2 + t * FF, h, y);
            k_node<<<N_ATOMS / 128, 256, 0, stream>>>(y, wout1T + t * 16384, bout1 + t * DD,
                                                      wout2T + t * 16384, bout2 + t * DD, r);
        }
    }
    k_head<<<N_ATOMS / 128, 256, 0, stream>>>(r, wa1T, ba1, wa2, ba2, mol, molE);
    k_out<<<N_MOLS / 256, 256, 0, stream>>>(molE, (float*)d_out);
}

// Round 6
// 1134.661 us; speedup vs baseline: 1.9523x; 1.3938x over previous
//
#include <hip/hip_runtime.h>
#include <hip/hip_bf16.h>

#define N_ATOMS 131072
#define N_EDGES 524288
#define N_MOLS  2048
#define DD      128   // n_atom_basis
#define FF      128   // n_filters
#define GG      50    // n_gaussians
#define TT      3

typedef __hip_bfloat16 bf16;
typedef __attribute__((ext_vector_type(8))) short short8;
typedef __attribute__((ext_vector_type(4))) float floatx4;

__device__ __forceinline__ float b2f(bf16 v) { return __bfloat162float(v); }
__device__ __forceinline__ bf16  f2b(float v) { return __float2bfloat16(v); }

// fast RNE float->bf16 (identical to RNE for finite values; no NaN handling —
// all values here are finite)
__device__ __forceinline__ unsigned short f2bu(float f) {
    unsigned u = __float_as_uint(f);
    u += 0x7fff + ((u >> 16) & 1);
    return (unsigned short)(u >> 16);
}
__device__ __forceinline__ bf16 f2b_fast(float f) {
    union { unsigned short u; bf16 b; } c; c.u = f2bu(f); return c.b;
}
// pack two floats as bf16x2 (lo at low address)
__device__ __forceinline__ unsigned int pk2(float lo, float hi) {
    return ((unsigned)f2bu(hi) << 16) | f2bu(lo);
}

__device__ __forceinline__ unsigned short b2us(bf16 v) {
    union { bf16 b; unsigned short u; } c; c.b = v; return c.u;
}

// unpack two bf16 (packed in a uint, low half = lower address) to float2
__device__ __forceinline__ float2 up2(unsigned int u) {
    float2 f;
    f.x = __uint_as_float(u << 16);
    f.y = __uint_as_float(u & 0xffff0000u);
    return f;
}

// shifted softplus: softplus(x) - ln2, fast HW-transcendental version.
// abs err ~1e-6 vs precise log1pf path — invisible at bf16 output precision.
__device__ __forceinline__ float sspf(float x) {
    float e = __expf(-fabsf(x));
    return fmaxf(x, 0.f) + __logf(1.f + e) - 0.69314718056f;
}

// ---------------------------------------------------------------------------
// MFMA helpers.
// 128-row variant (fallback path): A[128][136], wave owns rows [32w,32w+32).
// 64-row variant (main path): A[64][136], wave owns rows [16w,16w+16).
// B tile: [n][72] bf16 LDS holding B^T chunk: B[n][kk], kk<64.
// 16x16x32 bf16 layouts: A[m=lane&15][k=q*8+j], B[k=q*8+j][n=lane&15],
// D[row=q*4+reg][col=lane&15].  (verified, learn_hip m89)
// ---------------------------------------------------------------------------
template <int NCT>
__device__ __forceinline__ void mfma_half(const bf16* A, const bf16* B,
                                          floatx4 (&acc)[2][NCT],
                                          int kA, int wave, int q, int ln) {
#pragma unroll
    for (int k0 = 0; k0 < 64; k0 += 32) {
        short8 a0 = *(const short8*)(A + (wave * 32 + ln) * 136 + kA + k0 + q * 8);
        short8 a1 = *(const short8*)(A + (wave * 32 + 16 + ln) * 136 + kA + k0 + q * 8);
#pragma unroll
        for (int ct = 0; ct < NCT; ct++) {
            short8 b = *(const short8*)(B + (ct * 16 + ln) * 72 + k0 + q * 8);
            acc[0][ct] = __builtin_amdgcn_mfma_f32_16x16x32_bf16(a0, b, acc[0][ct], 0, 0, 0);
            acc[1][ct] = __builtin_amdgcn_mfma_f32_16x16x32_bf16(a1, b, acc[1][ct], 0, 0, 0);
        }
    }
}

template <int NCT>
__device__ __forceinline__ void mfma64(const bf16* A, const bf16* B,
                                       floatx4 (&acc)[NCT],
                                       int kA, int wave, int q, int ln) {
#pragma unroll
    for (int k0 = 0; k0 < 64; k0 += 32) {
        short8 a = *(const short8*)(A + (wave * 16 + ln) * 136 + kA + k0 + q * 8);
#pragma unroll
        for (int ct = 0; ct < NCT; ct++) {
            short8 b = *(const short8*)(B + (ct * 16 + ln) * 72 + k0 + q * 8);
            acc[ct] = __builtin_amdgcn_mfma_f32_16x16x32_bf16(a, b, acc[ct], 0, 0, 0);
        }
    }
}

__device__ __forceinline__ void stage_b(bf16* B, const bf16* WT, int k0,
                                        int nrows, int ldk, int tid) {
    for (int i = tid; i < nrows * 8; i += 256) {
        int n = i >> 3, kc = i & 7;
        *(short8*)(B + n * 72 + kc * 8) =
            *(const short8*)(WT + n * ldk + k0 + kc * 8);
    }
}

// ---------------------------------------------------------------------------
__global__ __launch_bounds__(256) void k_init(const float* __restrict__ emb,
                                              const int* __restrict__ z,
                                              float* __restrict__ r) {
    int idx = blockIdx.x * 256 + threadIdx.x;
    int atom = idx >> 7, col = idx & 127;
    r[idx] = emb[z[atom] * DD + col];
}

__global__ __launch_bounds__(256) void k_dist(const float* __restrict__ xyz,
                                              const int* __restrict__ a,
                                              float* __restrict__ dArr,
                                              float* __restrict__ cArr,
                                              float* __restrict__ molE) {
    int e = blockIdx.x * 256 + threadIdx.x;
    if (e < N_MOLS) molE[e] = 0.f;
    int A0 = a[2 * e], A1 = a[2 * e + 1];
    float dx = xyz[3 * A0]     - xyz[3 * A1];
    float dy = xyz[3 * A0 + 1] - xyz[3 * A1 + 1];
    float dz = xyz[3 * A0 + 2] - xyz[3 * A1 + 2];
    float d = sqrtf(dx * dx + dy * dy + dz * dz);
    dArr[e] = d;
    cArr[e] = 0.5f * (__cosf(d * 0.6283185307179586f) + 1.f);
}

__global__ __launch_bounds__(256) void k_wt(const float* __restrict__ fw1,
                                            const float* __restrict__ fw2,
                                            const float* __restrict__ win,
                                            const float* __restrict__ wout1,
                                            const float* __restrict__ wout2,
                                            const float* __restrict__ wa1,
                                            bf16* __restrict__ fw1T, bf16* __restrict__ fw2T,
                                            bf16* __restrict__ winT, bf16* __restrict__ wout1T,
                                            bf16* __restrict__ wout2T, bf16* __restrict__ wa1T) {
    int idx = blockIdx.x * 256 + threadIdx.x;
    if (idx < 3 * 128 * 64) {
        int t = idx / 8192, j = idx % 8192;
        int n = j >> 6, k = j & 63;
        fw1T[idx] = (k < GG) ? f2b(fw1[t * GG * FF + k * FF + n]) : f2b(0.f);
        return;
    }
    idx -= 3 * 128 * 64;
    if (idx < 3 * 16384) { int t = idx / 16384, j = idx % 16384; int n = j >> 7, k = j & 127;
        fw2T[idx] = f2b(fw2[t * 16384 + k * 128 + n]); return; }
    idx -= 3 * 16384;
    if (idx < 3 * 16384) { int t = idx / 16384, j = idx % 16384; int n = j >> 7, k = j & 127;
        winT[idx] = f2b(win[t * 16384 + k * 128 + n]); return; }
    idx -= 3 * 16384;
    if (idx < 3 * 16384) { int t = idx / 16384, j = idx % 16384; int n = j >> 7, k = j & 127;
        wout1T[idx] = f2b(wout1[t * 16384 + k * 128 + n]); return; }
    idx -= 3 * 16384;
    if (idx < 3 * 16384) { int t = idx / 16384, j = idx % 16384; int n = j >> 7, k = j & 127;
        wout2T[idx] = f2b(wout2[t * 16384 + k * 128 + n]); return; }
    idx -= 3 * 16384;
    if (idx < 64 * 128) { int n = idx >> 7, k = idx & 127;
        wa1T[idx] = f2b(wa1[k * 64 + n]); return; }
}

// ---------------------------------------------------------------------------
// CSR build (once per launch; edge list is constant across t)
__global__ __launch_bounds__(256) void k_zero(int* __restrict__ p, int n) {
    int i = blockIdx.x * 256 + threadIdx.x;
    if (i < n) p[i] = 0;
}

__global__ __launch_bounds__(256) void k_count(const int* __restrict__ a,
                                               int* __restrict__ counts) {
    int e = blockIdx.x * 256 + threadIdx.x;
    atomicAdd(&counts[a[2 * e]], 1);
    atomicAdd(&counts[a[2 * e + 1]], 1);
}

// single block: exclusive prefix sum of counts[N_ATOMS] -> ptr; cursor = ptr copy
__global__ __launch_bounds__(256) void k_scan(int* __restrict__ counts,
                                              int* __restrict__ ptr) {
    __shared__ int part[256];
    int tid = threadIdx.x;
    const int CH = N_ATOMS / 256;  // 512
    int base = tid * CH;
    int s = 0;
    for (int i = 0; i < CH; i++) s += counts[base + i];
    part[tid] = s;
    __syncthreads();
    if (tid == 0) {
        int acc = 0;
        for (int i = 0; i < 256; i++) { int v = part[i]; part[i] = acc; acc += v; }
    }
    __syncthreads();
    int run = part[tid];
    for (int i = 0; i < CH; i++) {
        int v = counts[base + i];
        ptr[base + i] = run;
        counts[base + i] = run;   // counts buffer becomes the fill cursor
        run += v;
    }
    if (tid == 255) ptr[N_ATOMS] = run;  // == 2E
}

// adj[slot] = (edge id, other atom)  -- slots contiguous per atom
__global__ __launch_bounds__(256) void k_fill(const int* __restrict__ a,
                                              int* __restrict__ cursor,
                                              int* __restrict__ adj) {
    int e = blockIdx.x * 256 + threadIdx.x;
    int A0 = a[2 * e], A1 = a[2 * e + 1];
    int p0 = atomicAdd(&cursor[A0], 1);
    adj[2 * p0] = e; adj[2 * p0 + 1] = A1;
    int p1 = atomicAdd(&cursor[A1], 1);
    adj[2 * p1] = e; adj[2 * p1 + 1] = A0;
}

// ---------------------------------------------------------------------------
// MAIN PATH: 64-row tiles, ~37 KB LDS -> 4 blocks/CU (16 waves)
// ---------------------------------------------------------------------------

// h = bf16(r) @ win[t]
__global__ __launch_bounds__(256, 4) void k_h64(const float* __restrict__ r,
                                                const bf16* __restrict__ winT_t,
                                                bf16* __restrict__ h) {
    __shared__ __align__(16) bf16 A[64][136];
    __shared__ __align__(16) bf16 B[128][72];
    int tid = threadIdx.x, n0 = blockIdx.x * 64;
    for (int i = tid; i < 64 * 32; i += 256) {
        int row = i >> 5, c4 = (i & 31) * 4;
        float4 v = *(const float4*)(r + (size_t)(n0 + row) * DD + c4);
        uint2 p; p.x = pk2(v.x, v.y); p.y = pk2(v.z, v.w);
        *(uint2*)(&A[row][c4]) = p;
    }
    stage_b(&B[0][0], winT_t, 0, 128, 128, tid);
    __syncthreads();
    int wave = tid >> 6, lane = tid & 63, q = lane >> 4, ln = lane & 15;
    floatx4 acc[8];
#pragma unroll
    for (int j = 0; j < 8; j++) acc[j] = (floatx4){0.f, 0.f, 0.f, 0.f};
    mfma64<8>(&A[0][0], &B[0][0], acc, 0, wave, q, ln);
    __syncthreads();
    stage_b(&B[0][0], winT_t, 64, 128, 128, tid);
    __syncthreads();
    mfma64<8>(&A[0][0], &B[0][0], acc, 64, wave, q, ln);
    // result -> A (own wave rows), then coalesced 16B global store
#pragma unroll
    for (int ct = 0; ct < 8; ct++)
#pragma unroll
        for (int rg = 0; rg < 4; rg++) {
            int row = wave * 16 + q * 4 + rg, col = ct * 16 + ln;
            A[row][col] = f2b_fast(acc[ct][rg]);
        }
    __syncthreads();
    for (int i = tid; i < 64 * 16; i += 256) {
        int row = i >> 4, seg = i & 15;
        *(uint4*)(h + (size_t)(n0 + row) * FF + seg * 8) =
            *(const uint4*)(&A[row][seg * 8]);
    }
}

// edge filter: Wt[e][:] = bf16( (ssp(g@fw1+b1)@fw2 + b2) * C )
__global__ __launch_bounds__(256, 4) void k_edge_w64(const float* __restrict__ dArr,
                                                     const float* __restrict__ cArr,
                                                     const bf16* __restrict__ fw1T_t,
                                                     const float* __restrict__ fb1_t,
                                                     const bf16* __restrict__ fw2T_t,
                                                     const float* __restrict__ fb2_t,
                                                     bf16* __restrict__ Wt) {
    __shared__ __align__(16) bf16 A[64][136];
    __shared__ __align__(16) bf16 B[128][72];
    __shared__ float dS[64], cS[64], b1S[128], b2S[128];
    int tid = threadIdx.x, e0 = blockIdx.x * 64;
    if (tid < 64) { dS[tid] = dArr[e0 + tid]; cS[tid] = cArr[e0 + tid]; }
    if (tid < 128) { b1S[tid] = fb1_t[tid]; b2S[tid] = fb2_t[tid]; }
    stage_b(&B[0][0], fw1T_t, 0, 128, 64, tid);
    __syncthreads();   // dS visible before g-smear
    const float width = 5.0f / 49.0f;
    const float coeff = -0.5f / (width * width);
    for (int idx = tid; idx < 64 * 32; idx += 256) {   // pairs
        int i = idx >> 5, kp = (idx & 31) * 2;
        float d = dS[i];
        float t0 = d - (float)kp * width;
        float t1 = d - (float)(kp + 1) * width;
        float v0 = (kp < GG)     ? __expf(coeff * t0 * t0) : 0.f;
        float v1 = (kp + 1 < GG) ? __expf(coeff * t1 * t1) : 0.f;
        *(unsigned int*)(&A[i][kp]) = pk2(v0, v1);
    }
    __syncthreads();
    int wave = tid >> 6, lane = tid & 63, q = lane >> 4, ln = lane & 15;
    floatx4 acc[8];
#pragma unroll
    for (int j = 0; j < 8; j++) acc[j] = (floatx4){0.f, 0.f, 0.f, 0.f};
    mfma64<8>(&A[0][0], &B[0][0], acc, 0, wave, q, ln);   // K=64 (padded from 50)
    // u = ssp(.+b1) -> A own rows (other waves never read our rows)
#pragma unroll
    for (int ct = 0; ct < 8; ct++)
#pragma unroll
        for (int rg = 0; rg < 4; rg++) {
            int row = wave * 16 + q * 4 + rg, col = ct * 16 + ln;
            A[row][col] = f2b_fast(sspf(acc[ct][rg] + b1S[col]));
        }
    __syncthreads();
    stage_b(&B[0][0], fw2T_t, 0, 128, 128, tid);
    __syncthreads();
#pragma unroll
    for (int j = 0; j < 8; j++) acc[j] = (floatx4){0.f, 0.f, 0.f, 0.f};
    mfma64<8>(&A[0][0], &B[0][0], acc, 0, wave, q, ln);
    __syncthreads();
    stage_b(&B[0][0], fw2T_t, 64, 128, 128, tid);
    __syncthreads();
    mfma64<8>(&A[0][0], &B[0][0], acc, 64, wave, q, ln);
#pragma unroll
    for (int ct = 0; ct < 8; ct++)
#pragma unroll
        for (int rg = 0; rg < 4; rg++) {
            int row = wave * 16 + q * 4 + rg, col = ct * 16 + ln;
            A[row][col] = f2b_fast((acc[ct][rg] + b2S[col]) * cS[row]);
        }
    __syncthreads();
    for (int i = tid; i < 64 * 16; i += 256) {
        int row = i >> 4, seg = i & 15;
        *(uint4*)(Wt + (size_t)(e0 + row) * FF + seg * 8) =
            *(const uint4*)(&A[row][seg * 8]);
    }
}

// cooperative gather (16B/lane, 4 slots in flight) + fused node MLP; r += dr
__global__ __launch_bounds__(256, 4) void k_gather_node64(const int* __restrict__ ptr,
                                                          const int* __restrict__ adj,
                                                          const bf16* __restrict__ Wt,
                                                          const bf16* __restrict__ h,
                                                          const bf16* __restrict__ wout1T_t,
                                                          const float* __restrict__ bo1_t,
                                                          const bf16* __restrict__ wout2T_t,
                                                          const float* __restrict__ bo2_t,
                                                          float* __restrict__ r) {
    __shared__ __align__(16) bf16 A[64][136];
    __shared__ __align__(16) bf16 B[128][72];
    __shared__ float b1S[128], b2S[128];
    int tid = threadIdx.x, n0 = blockIdx.x * 64;
    if (tid < 128) { b1S[tid] = bo1_t[tid]; b2S[tid] = bo2_t[tid]; }
    int wave = tid >> 6, lane = tid & 63;
    int seg = lane & 15;   // column segment: cols [8*seg, 8*seg+8)
    int rg  = lane >> 4;   // slot-in-group 0..3
    for (int k = 0; k < 16; k++) {
        int row = wave * 16 + k;
        int atom = n0 + row;
        int beg = ptr[atom], end = ptr[atom + 1];
        float ac[8];
#pragma unroll
        for (int j = 0; j < 8; j++) ac[j] = 0.f;
        for (int s0 = beg; s0 < end; s0 += 4) {
            int slot = s0 + rg;
            if (slot < end) {
                int2 eo = *(const int2*)(adj + 2 * slot);
                uint4 wv = *(const uint4*)(Wt + (size_t)eo.x * FF + seg * 8);
                uint4 hv = *(const uint4*)(h + (size_t)eo.y * FF + seg * 8);
                float2 w0 = up2(wv.x), h0 = up2(hv.x);
                float2 w1 = up2(wv.y), h1 = up2(hv.y);
                float2 w2 = up2(wv.z), h2 = up2(hv.z);
                float2 w3 = up2(wv.w), h3 = up2(hv.w);
                ac[0] = fmaf(w0.x, h0.x, ac[0]); ac[1] = fmaf(w0.y, h0.y, ac[1]);
                ac[2] = fmaf(w1.x, h1.x, ac[2]); ac[3] = fmaf(w1.y, h1.y, ac[3]);
                ac[4] = fmaf(w2.x, h2.x, ac[4]); ac[5] = fmaf(w2.y, h2.y, ac[5]);
                ac[6] = fmaf(w3.x, h3.x, ac[6]); ac[7] = fmaf(w3.y, h3.y, ac[7]);
            }
        }
        // reduce over the 4 slot-groups (lanes rg=0..3 at stride 16)
#pragma unroll
        for (int j = 0; j < 8; j++) {
            float v = ac[j];
            v += __shfl_down(v, 32);
            v += __shfl_down(v, 16);
            ac[j] = v;
        }
        if (rg == 0) {
            uint4 o;
            o.x = pk2(ac[0], ac[1]);
            o.y = pk2(ac[2], ac[3]);
            o.z = pk2(ac[4], ac[5]);
            o.w = pk2(ac[6], ac[7]);
            *(uint4*)(&A[row][seg * 8]) = o;
        }
    }
    stage_b(&B[0][0], wout1T_t, 0, 128, 128, tid);
    __syncthreads();
    int q = lane >> 4, ln = lane & 15;
    floatx4 acc[8];
#pragma unroll
    for (int j = 0; j < 8; j++) acc[j] = (floatx4){0.f, 0.f, 0.f, 0.f};
    mfma64<8>(&A[0][0], &B[0][0], acc, 0, wave, q, ln);
    __syncthreads();
    stage_b(&B[0][0], wout1T_t, 64, 128, 128, tid);
    __syncthreads();
    mfma64<8>(&A[0][0], &B[0][0], acc, 64, wave, q, ln);
#pragma unroll
    for (int ct = 0; ct < 8; ct++)
#pragma unroll
        for (int rgi = 0; rgi < 4; rgi++) {
            int row = wave * 16 + q * 4 + rgi, col = ct * 16 + ln;
            A[row][col] = f2b_fast(sspf(acc[ct][rgi] + b1S[col]));
        }
    __syncthreads();
    stage_b(&B[0][0], wout2T_t, 0, 128, 128, tid);
    __syncthreads();
#pragma unroll
    for (int j = 0; j < 8; j++) acc[j] = (floatx4){0.f, 0.f, 0.f, 0.f};
    mfma64<8>(&A[0][0], &B[0][0], acc, 0, wave, q, ln);
    __syncthreads();
    stage_b(&B[0][0], wout2T_t, 64, 128, 128, tid);
    __syncthreads();
    mfma64<8>(&A[0][0], &B[0][0], acc, 64, wave, q, ln);
#pragma unroll
    for (int ct = 0; ct < 8; ct++)
#pragma unroll
        for (int rgi = 0; rgi < 4; rgi++) {
            int row = wave * 16 + q * 4 + rgi, col = ct * 16 + ln;
            size_t off = (size_t)(n0 + row) * DD + col;
            r[off] += acc[ct][rgi] + b2S[col];
        }
}

// ---------------------------------------------------------------------------
// FALLBACK (round-2 verified): fused atomic scatter + separate k_h/k_node
// ---------------------------------------------------------------------------
__global__ __launch_bounds__(256) void k_h(const float* __restrict__ r,
                                           const bf16* __restrict__ winT_t,
                                           bf16* __restrict__ h,
                                           float* __restrict__ y) {
    __shared__ __align__(16) bf16 A[128][136];
    __shared__ __align__(16) bf16 B[128][72];
    int tid = threadIdx.x, n0 = blockIdx.x * 128;
    for (int i = tid; i < 128 * 32; i += 256) {
        int row = i >> 5, c4 = (i & 31) * 4;
        float4 v = *(const float4*)(r + (size_t)(n0 + row) * DD + c4);
        A[row][c4]     = f2b(v.x);
        A[row][c4 + 1] = f2b(v.y);
        A[row][c4 + 2] = f2b(v.z);
        A[row][c4 + 3] = f2b(v.w);
        *(float4*)(y + (size_t)(n0 + row) * FF + c4) = (float4){0.f, 0.f, 0.f, 0.f};
    }
    stage_b(&B[0][0], winT_t, 0, 128, 128, tid);
    __syncthreads();
    int wave = tid >> 6, lane = tid & 63, q = lane >> 4, ln = lane & 15;
    floatx4 acc[2][8];
#pragma unroll
    for (int i = 0; i < 2; i++)
#pragma unroll
        for (int j = 0; j < 8; j++) acc[i][j] = (floatx4){0.f, 0.f, 0.f, 0.f};
    mfma_half<8>(&A[0][0], &B[0][0], acc, 0, wave, q, ln);
    __syncthreads();
    stage_b(&B[0][0], winT_t, 64, 128, 128, tid);
    __syncthreads();
    mfma_half<8>(&A[0][0], &B[0][0], acc, 64, wave, q, ln);
#pragma unroll
    for (int rt = 0; rt < 2; rt++)
#pragma unroll
        for (int ct = 0; ct < 8; ct++)
#pragma unroll
            for (int rg = 0; rg < 4; rg++) {
                int row = wave * 32 + rt * 16 + q * 4 + rg, col = ct * 16 + ln;
                h[(size_t)(n0 + row) * FF + col] = f2b(acc[rt][ct][rg]);
            }
}

__global__ __launch_bounds__(256) void k_edge(const float* __restrict__ dArr,
                                              const float* __restrict__ cArr,
                                              const int* __restrict__ a,
                                              const bf16* __restrict__ fw1T_t,
                                              const float* __restrict__ fb1_t,
                                              const bf16* __restrict__ fw2T_t,
                                              const float* __restrict__ fb2_t,
                                              const bf16* __restrict__ h,
                                              float* __restrict__ y) {
    __shared__ __align__(16) bf16 A[128][136];
    __shared__ __align__(16) bf16 B[128][72];
    __shared__ float dS[128], cS[128], b1S[128], b2S[128];
    __shared__ int a0S[128], a1S[128];
    int tid = threadIdx.x, e0 = blockIdx.x * 128;
    if (tid < 128) {
        int e = e0 + tid;
        dS[tid] = dArr[e]; cS[tid] = cArr[e];
        a0S[tid] = a[2 * e]; a1S[tid] = a[2 * e + 1];
        b1S[tid] = fb1_t[tid]; b2S[tid] = fb2_t[tid];
    }
    stage_b(&B[0][0], fw1T_t, 0, 128, 64, tid);
    __syncthreads();
    const float width = 5.0f / 49.0f;
    const float coeff = -0.5f / (width * width);
    for (int idx = tid; idx < 128 * 64; idx += 256) {
        int i = idx >> 6, k = idx & 63;
        float v = 0.f;
        if (k < GG) { float t = dS[i] - (float)k * width; v = __expf(coeff * t * t); }
        A[i][k] = f2b(v);
    }
    __syncthreads();
    int wave = tid >> 6, lane = tid & 63, q = lane >> 4, ln = lane & 15;
    floatx4 acc[2][8];
#pragma unroll
    for (int i = 0; i < 2; i++)
#pragma unroll
        for (int j = 0; j < 8; j++) acc[i][j] = (floatx4){0.f, 0.f, 0.f, 0.f};
    mfma_half<8>(&A[0][0], &B[0][0], acc, 0, wave, q, ln);
#pragma unroll
    for (int rt = 0; rt < 2; rt++)
#pragma unroll
        for (int ct = 0; ct < 8; ct++)
#pragma unroll
            for (int rg = 0; rg < 4; rg++) {
                int row = wave * 32 + rt * 16 + q * 4 + rg, col = ct * 16 + ln;
                A[row][col] = f2b(sspf(acc[rt][ct][rg] + b1S[col]));
            }
    __syncthreads();
    stage_b(&B[0][0], fw2T_t, 0, 128, 128, tid);
    __syncthreads();
#pragma unroll
    for (int i = 0; i < 2; i++)
#pragma unroll
        for (int j = 0; j < 8; j++) acc[i][j] = (floatx4){0.f, 0.f, 0.f, 0.f};
    mfma_half<8>(&A[0][0], &B[0][0], acc, 0, wave, q, ln);
    __syncthreads();
    stage_b(&B[0][0], fw2T_t, 64, 128, 128, tid);
    __syncthreads();
    mfma_half<8>(&A[0][0], &B[0][0], acc, 64, wave, q, ln);
#pragma unroll
    for (int rt = 0; rt < 2; rt++)
#pragma unroll
        for (int ct = 0; ct < 8; ct++)
#pragma unroll
            for (int rg = 0; rg < 4; rg++) {
                int row = wave * 32 + rt * 16 + q * 4 + rg, col = ct * 16 + ln;
                float w = (acc[rt][ct][rg] + b2S[col]) * cS[row];
                int A0 = a0S[row], A1 = a1S[row];
                float h0 = b2f(h[A0 * FF + col]);
                float h1 = b2f(h[A1 * FF + col]);
                atomicAdd(&y[A0 * FF + col], h1 * w);
                atomicAdd(&y[A1 * FF + col], h0 * w);
            }
}

__global__ __launch_bounds__(256) void k_node(const float* __restrict__ y,
                                              const bf16* __restrict__ wout1T_t,
                                              const float* __restrict__ bo1_t,
                                              const bf16* __restrict__ wout2T_t,
                                              const float* __restrict__ bo2_t,
                                              float* __restrict__ r) {
    __shared__ __align__(16) bf16 A[128][136];
    __shared__ __align__(16) bf16 B[128][72];
    __shared__ float b1S[128], b2S[128];
    int tid = threadIdx.x, n0 = blockIdx.x * 128;
    if (tid < 128) { b1S[tid] = bo1_t[tid]; b2S[tid] = bo2_t[tid]; }
    for (int idx = tid; idx < 128 * 128; idx += 256) {
        int row = idx >> 7, col = idx & 127;
        A[row][col] = f2b(y[(size_t)(n0 + row) * FF + col]);
    }
    stage_b(&B[0][0], wout1T_t, 0, 128, 128, tid);
    __syncthreads();
    int wave = tid >> 6, lane = tid & 63, q = lane >> 4, ln = lane & 15;
    floatx4 acc[2][8];
#pragma unroll
    for (int i = 0; i < 2; i++)
#pragma unroll
        for (int j = 0; j < 8; j++) acc[i][j] = (floatx4){0.f, 0.f, 0.f, 0.f};
    mfma_half<8>(&A[0][0], &B[0][0], acc, 0, wave, q, ln);
    __syncthreads();
    stage_b(&B[0][0], wout1T_t, 64, 128, 128, tid);
    __syncthreads();
    mfma_half<8>(&A[0][0], &B[0][0], acc, 64, wave, q, ln);
#pragma unroll
    for (int rt = 0; rt < 2; rt++)
#pragma unroll
        for (int ct = 0; ct < 8; ct++)
#pragma unroll
            for (int rg = 0; rg < 4; rg++) {
                int row = wave * 32 + rt * 16 + q * 4 + rg, col = ct * 16 + ln;
                A[row][col] = f2b(sspf(acc[rt][ct][rg] + b1S[col]));
            }
    __syncthreads();
    stage_b(&B[0][0], wout2T_t, 0, 128, 128, tid);
    __syncthreads();
#pragma unroll
    for (int i = 0; i < 2; i++)
#pragma unroll
        for (int j = 0; j < 8; j++) acc[i][j] = (floatx4){0.f, 0.f, 0.f, 0.f};
    mfma_half<8>(&A[0][0], &B[0][0], acc, 0, wave, q, ln);
    __syncthreads();
    stage_b(&B[0][0], wout2T_t, 64, 128, 128, tid);
    __syncthreads();
    mfma_half<8>(&A[0][0], &B[0][0], acc, 64, wave, q, ln);
#pragma unroll
    for (int rt = 0; rt < 2; rt++)
#pragma unroll
        for (int ct = 0; ct < 8; ct++)
#pragma unroll
            for (int rg = 0; rg < 4; rg++) {
                int row = wave * 32 + rt * 16 + q * 4 + rg, col = ct * 16 + ln;
                size_t off = (size_t)(n0 + row) * DD + col;
                r[off] += acc[rt][ct][rg] + b2S[col];
            }
}

// ---------------------------------------------------------------------------
__global__ __launch_bounds__(256) void k_head(const float* __restrict__ r,
                                              const bf16* __restrict__ wa1T,
                                              const float* __restrict__ ba1,
                                              const float* __restrict__ wa2,
                                              const float* __restrict__ ba2,
                                              const int* __restrict__ mol,
                                              float* __restrict__ molE) {
    __shared__ __align__(16) bf16 A[128][136];
    __shared__ __align__(16) bf16 B[64][72];
    __shared__ __align__(16) bf16 U[128][72];
    __shared__ float wa2S[64], ba1S[64];
    int tid = threadIdx.x, n0 = blockIdx.x * 128;
    if (tid < 64) { wa2S[tid] = wa2[tid]; ba1S[tid] = ba1[tid]; }
    for (int i = tid; i < 128 * 32; i += 256) {
        int row = i >> 5, c4 = (i & 31) * 4;
        float4 v = *(const float4*)(r + (size_t)(n0 + row) * DD + c4);
        uint2 p; p.x = pk2(v.x, v.y); p.y = pk2(v.z, v.w);
        *(uint2*)(&A[row][c4]) = p;
    }
    stage_b(&B[0][0], wa1T, 0, 64, 128, tid);
    __syncthreads();
    int wave = tid >> 6, lane = tid & 63, q = lane >> 4, ln = lane & 15;
    floatx4 acc[2][4];
#pragma unroll
    for (int i = 0; i < 2; i++)
#pragma unroll
        for (int j = 0; j < 4; j++) acc[i][j] = (floatx4){0.f, 0.f, 0.f, 0.f};
    mfma_half<4>(&A[0][0], &B[0][0], acc, 0, wave, q, ln);
    __syncthreads();
    stage_b(&B[0][0], wa1T, 64, 64, 128, tid);
    __syncthreads();
    mfma_half<4>(&A[0][0], &B[0][0], acc, 64, wave, q, ln);
#pragma unroll
    for (int rt = 0; rt < 2; rt++)
#pragma unroll
        for (int ct = 0; ct < 4; ct++)
#pragma unroll
            for (int rg = 0; rg < 4; rg++) {
                int row = wave * 32 + rt * 16 + q * 4 + rg, col = ct * 16 + ln;
                U[row][col] = f2b_fast(acc[rt][ct][rg] + ba1S[col]);
            }
    __syncthreads();
    if (tid < 128) {
        float s = ba2[0];
#pragma unroll
        for (int j = 0; j < 64; j++) s += sspf(b2f(U[tid][j])) * wa2S[j];
        atomicAdd(&molE[mol[n0 + tid]], s);
    }
}

__global__ __launch_bounds__(256) void k_out(const float* __restrict__ molE,
                                             float* __restrict__ out) {
    int i = blockIdx.x * 256 + threadIdx.x;
    out[i] = molE[i];
}

// ---------------------------------------------------------------------------
extern "C" void kernel_launch(void* const* d_in, const int* in_sizes, int n_in,
                              void* d_out, int out_size, void* d_ws, size_t ws_size,
                              hipStream_t stream) {
    const float* xyz   = (const float*)d_in[0];
    const float* emb   = (const float*)d_in[1];
    const float* fw1   = (const float*)d_in[2];
    const float* fb1   = (const float*)d_in[3];
    const float* fw2   = (const float*)d_in[4];
    const float* fb2   = (const float*)d_in[5];
    const float* win   = (const float*)d_in[6];
    const float* wout1 = (const float*)d_in[7];
    const float* bout1 = (const float*)d_in[8];
    const float* wout2 = (const float*)d_in[9];
    const float* bout2 = (const float*)d_in[10];
    const float* wa1   = (const float*)d_in[11];
    const float* ba1   = (const float*)d_in[12];
    const float* wa2   = (const float*)d_in[13];
    const float* ba2   = (const float*)d_in[14];
    const int*  z     = (const int*)d_in[15];
    const int*  a     = (const int*)d_in[16];
    const int*  mol   = (const int*)d_in[17];

    // layout identical to round-3 (need == 248,979,472 — proven to fit)
    char* ws = (char*)d_ws;
    float* r    = (float*)ws; ws += (size_t)N_ATOMS * DD * 4;     //  67,108,864
    bf16*  h    = (bf16*) ws; ws += (size_t)N_ATOMS * FF * 2;     //  33,554,432
    float* dA   = (float*)ws; ws += (size_t)N_EDGES * 4;          //   2,097,152
    float* cA   = (float*)ws; ws += (size_t)N_EDGES * 4;          //   2,097,152
    float* molE = (float*)ws; ws += (size_t)N_MOLS * 4;           //       8,192
    bf16*  fw1T   = (bf16*)ws; ws += 3 * 128 * 64 * 2;
    bf16*  fw2T   = (bf16*)ws; ws += 3 * 128 * 128 * 2;
    bf16*  winT   = (bf16*)ws; ws += 3 * 128 * 128 * 2;
    bf16*  wout1T = (bf16*)ws; ws += 3 * 128 * 128 * 2;
    bf16*  wout2T = (bf16*)ws; ws += 3 * 128 * 128 * 2;
    bf16*  wa1T   = (bf16*)ws; ws += 64 * 128 * 2;
    char*  csr_base = ws;                                          // fallback y aliases here
    int*   ptr    = (int*)ws;  ws += 524304;                      // N_ATOMS+1 ints, padded
    int*   cursor = (int*)ws;  ws += (size_t)N_ATOMS * 4;
    int*   adj    = (int*)ws;  ws += (size_t)2 * N_EDGES * 2 * 4; //   8,388,608
    bf16*  Wt     = (bf16*)ws; ws += (size_t)N_EDGES * FF * 2;    // 134,217,728
    size_t need = (size_t)(ws - (char*)d_ws);                     // 248,979,472

    k_init<<<N_ATOMS * DD / 256, 256, 0, stream>>>(emb, z, r);
    k_dist<<<N_EDGES / 256, 256, 0, stream>>>(xyz, a, dA, cA, molE);
    k_wt<<<896, 256, 0, stream>>>(fw1, fw2, win, wout1, wout2, wa1,
                                  fw1T, fw2T, winT, wout1T, wout2T, wa1T);

    if (ws_size >= need) {
        k_zero<<<(N_ATOMS + 255) / 256, 256, 0, stream>>>(cursor, N_ATOMS);
        k_count<<<N_EDGES / 256, 256, 0, stream>>>(a, cursor);
        k_scan<<<1, 256, 0, stream>>>(cursor, ptr);
        k_fill<<<N_EDGES / 256, 256, 0, stream>>>(a, cursor, adj);
        for (int t = 0; t < TT; t++) {
            k_h64<<<N_ATOMS / 64, 256, 0, stream>>>(r, winT + t * 16384, h);
            k_edge_w64<<<N_EDGES / 64, 256, 0, stream>>>(dA, cA,
                                                         fw1T + t * 8192, fb1 + t * FF,
                                                         fw2T + t * 16384, fb2 + t * FF, Wt);
            k_gather_node64<<<N_ATOMS / 64, 256, 0, stream>>>(ptr, adj, Wt, h,
                                                              wout1T + t * 16384, bout1 + t * DD,
                                                              wout2T + t * 16384, bout2 + t * DD, r);
        }
    } else {
        // fallback: round-2 verified atomic-scatter path (y aliases CSR region)
        float* y = (float*)csr_base;
        for (int t = 0; t < TT; t++) {
            k_h<<<N_ATOMS / 128, 256, 0, stream>>>(r, winT + t * 16384, h, y);
            k_edge<<<N_EDGES / 128, 256, 0, stream>>>(dA, cA, a,
                                                      fw1T + t * 8192, fb1 + t * FF,
                                                      fw2T + t * 16384, fb2 + t * FF, h, y);
            k_node<<<N_ATOMS / 128, 256, 0, stream>>>(y, wout1T + t * 16384, bout1 + t * DD,
                                                      wout2T + t * 16384, bout2 + t * DD, r);
        }
    }
    k_head<<<N_ATOMS / 128, 256, 0, stream>>>(r, wa1T, ba1, wa2, ba2, mol, molE);
    k_out<<<N_MOLS / 256, 256, 0, stream>>>(molE, (float*)d_out);
}